// Round 3
// baseline (1449.667 us; speedup 1.0000x reference)
//
#include <hip/hip_runtime.h>
#include <hip/hip_bf16.h>
#include <math.h>

// Problem constants
#define B_   32
#define S_   128          // S1 == S2 == 128
#define V_   30000
#define D_   300
#define P_   200
#define NT   8192         // 2*B*S token rows: x1 rows 0..4095, x2 rows 4096..8191
#define NT1  4096

typedef __hip_bfloat16 bf16;

__device__ __forceinline__ float b2f(bf16 v) { return __bfloat162float(v); }
__device__ __forceinline__ float ldf(const bf16* p)  { return __bfloat162float(*p); }
__device__ __forceinline__ float ldf(const float* p) { return *p; }
__device__ __forceinline__ void  stf(bf16* p, float v)  { *p = __float2bfloat16(v); }
__device__ __forceinline__ void  stf(float* p, float v) { *p = v; }

// ---------------------------------------------------------------------------
// Dtype detector: interpret first 8192 u16 words of emb as bf16. Genuine bf16
// N(0,1) data never has biased exponent > 140 (|v| <= ~2^13); fp32 storage's
// low mantissa halves are ~uniform -> ~25% exceed. flag=1 means "fp32 storage".
// ---------------------------------------------------------------------------
__global__ void k_detect(const unsigned short* __restrict__ emb16, int* __restrict__ flag) {
    __shared__ int cnt;
    if (threadIdx.x == 0) cnt = 0;
    __syncthreads();
    int c = 0;
    for (int i = threadIdx.x; i < 8192; i += 256) {
        unsigned short u = emb16[i];
        int e = (u >> 7) & 0xFF;
        if (e > 140) c++;
    }
    atomicAdd(&cnt, c);
    __syncthreads();
    if (threadIdx.x == 0) *flag = (cnt > 16) ? 1 : 0;
}

// ---------------------------------------------------------------------------
// Embedding gather -> bf16 ws. emb dtype chosen by flag (uniform branch).
// ---------------------------------------------------------------------------
__global__ void k_embed(const int* __restrict__ x1, const int* __restrict__ x2,
                        const void* __restrict__ emb, bf16* __restrict__ E,
                        const int* __restrict__ flag) {
    int f = *flag;
    int idx = blockIdx.x * 256 + threadIdx.x;
    if (idx >= NT * D_) return;
    int r = idx / D_;
    int d = idx - r * D_;
    int tok = (r < NT1) ? x1[r] : x2[r - NT1];
    if ((unsigned)tok >= (unsigned)V_) tok = 0;
    float v;
    if (f) v = ((const float*)emb)[(size_t)tok * D_ + d];
    else   v = b2f(((const bf16*)emb)[(size_t)tok * D_ + d]);
    E[idx] = __float2bfloat16(v);
}

// ---------------------------------------------------------------------------
// Generic tiled GEMM: C[M,N] = act(A[M,K] @ W[K,N] + bias[N])
// A: TI ws storage. W/bias: input tensors, dtype per flag. fp32 accumulate.
// act: 0=none, 1=relu, 2=sigmoid.
// CAT=1: logical A = concat([E, ATT, E-ATT, E*ATT], -1), K=4*D_=1200.
// ---------------------------------------------------------------------------
#define BM 64
#define BN 64
#define BK 16

template <int CAT, typename TI, typename TO>
__global__ __launch_bounds__(256) void k_gemm(
    const TI* __restrict__ A, const TI* __restrict__ A2,
    const void* __restrict__ W, const void* __restrict__ bias,
    TO* __restrict__ C, int M, int N, int K, int act,
    const int* __restrict__ flag) {
    const int f = *flag;
    __shared__ float As[BK][BM + 1];
    __shared__ float Ws[BK][BN + 1];
    int tid = threadIdx.x;
    int bm = blockIdx.y * BM;
    int bn = blockIdx.x * BN;
    int tx = tid & 15, ty = tid >> 4;
    float acc[4][4] = {};
    for (int k0 = 0; k0 < K; k0 += BK) {
#pragma unroll
        for (int l = 0; l < 4; ++l) {          // A tile: 64 rows x 16 k
            int idx = tid + l * 256;
            int m = idx >> 4;
            int kk = idx & 15;
            int gm = bm + m, gk = k0 + kk;
            float v = 0.f;
            if (gm < M && gk < K) {
                if (CAT == 0) {
                    v = ldf(&A[(size_t)gm * K + gk]);
                } else {
                    int sel = gk / D_;
                    int kc = gk - sel * D_;
                    float e = ldf(&A[(size_t)gm * D_ + kc]);
                    float a = ldf(&A2[(size_t)gm * D_ + kc]);
                    v = (sel == 0) ? e : (sel == 1) ? a : (sel == 2) ? (e - a) : (e * a);
                }
            }
            As[kk][m] = v;
        }
        // W tile: 16 k x 64 n — real if/else so the untaken dtype path's loads
        // never execute (avoids speculative OOB reads).
        if (f) {
#pragma unroll
            for (int l = 0; l < 4; ++l) {
                int idx = tid + l * 256;
                int kk = idx >> 6;
                int n = idx & 63;
                int gk = k0 + kk, gn = bn + n;
                float v = 0.f;
                if (gk < K && gn < N) v = ((const float*)W)[(size_t)gk * N + gn];
                Ws[kk][n] = v;
            }
        } else {
#pragma unroll
            for (int l = 0; l < 4; ++l) {
                int idx = tid + l * 256;
                int kk = idx >> 6;
                int n = idx & 63;
                int gk = k0 + kk, gn = bn + n;
                float v = 0.f;
                if (gk < K && gn < N) v = b2f(((const bf16*)W)[(size_t)gk * N + gn]);
                Ws[kk][n] = v;
            }
        }
        __syncthreads();
#pragma unroll
        for (int kk = 0; kk < BK; ++kk) {
            float a[4], w[4];
#pragma unroll
            for (int i = 0; i < 4; ++i) a[i] = As[kk][ty * 4 + i];
#pragma unroll
            for (int j = 0; j < 4; ++j) w[j] = Ws[kk][tx * 4 + j];
#pragma unroll
            for (int i = 0; i < 4; ++i)
#pragma unroll
                for (int j = 0; j < 4; ++j) acc[i][j] += a[i] * w[j];
        }
        __syncthreads();
    }
#pragma unroll
    for (int i = 0; i < 4; ++i) {
        int gm = bm + ty * 4 + i;
        if (gm >= M) continue;
#pragma unroll
        for (int j = 0; j < 4; ++j) {
            int gn = bn + tx * 4 + j;
            if (gn >= N) continue;
            float bv;
            if (f) bv = ((const float*)bias)[gn];
            else   bv = b2f(((const bf16*)bias)[gn]);
            float v = acc[i][j] + bv;
            if (act == 1) v = fmaxf(v, 0.f);
            else if (act == 2) v = 1.f / (1.f + expf(-v));
            stf(&C[(size_t)gm * N + gn], v);
        }
    }
}

// ---------------------------------------------------------------------------
// Highway combine: X = T*H + (1-T)*X  (elementwise, in place, bf16)
// ---------------------------------------------------------------------------
__global__ void k_highway(const bf16* __restrict__ H, const bf16* __restrict__ T,
                          bf16* __restrict__ X, int n) {
    int i = blockIdx.x * 256 + threadIdx.x;
    if (i < n) {
        float t = ldf(&T[i]);
        float h = ldf(&H[i]);
        float x = ldf(&X[i]);
        stf(&X[i], t * h + (1.f - t) * x);
    }
}

// ---------------------------------------------------------------------------
// Transpose x2-half of [NT,P] into [B,P,S] (bf16 copy, exact)
// ---------------------------------------------------------------------------
__global__ void k_transpose(const bf16* __restrict__ src, bf16* __restrict__ dst) {
    int idx = blockIdx.x * 256 + threadIdx.x;
    if (idx >= B_ * P_ * S_) return;
    int j = idx & (S_ - 1);
    int rest = idx >> 7;
    int p = rest % P_;
    int b = rest / P_;
    dst[idx] = src[((size_t)(b * S_ + j)) * P_ + p];
}

// ---------------------------------------------------------------------------
// sim[b,i,j] = dot_p(p1,p2) + sum_p 1/(1+|q1-q2|); block=b*128+i, thread=j
// ---------------------------------------------------------------------------
__global__ __launch_bounds__(128) void k_sim(const bf16* __restrict__ Pmat,
                                             const bf16* __restrict__ Qmat,
                                             const bf16* __restrict__ PT,
                                             const bf16* __restrict__ QT,
                                             float* __restrict__ SIM) {
    int bi = blockIdx.x;
    int b = bi >> 7;
    int j = threadIdx.x;
    __shared__ float p1[P_], q1[P_];
    const bf16* prow = Pmat + (size_t)bi * P_;   // rows 0..4095 = x1 tokens
    const bf16* qrow = Qmat + (size_t)bi * P_;
    for (int t = j; t < P_; t += 128) { p1[t] = ldf(&prow[t]); q1[t] = ldf(&qrow[t]); }
    __syncthreads();
    const bf16* pt = PT + (size_t)b * P_ * S_;
    const bf16* qt = QT + (size_t)b * P_ * S_;
    float acc1 = 0.f, acc2 = 0.f;
    for (int p = 0; p < P_; ++p) {
        float v = ldf(&pt[p * S_ + j]);
        float u = ldf(&qt[p * S_ + j]);
        acc1 += p1[p] * v;
        acc2 += 1.f / (1.f + fabsf(q1[p] - u));
    }
    SIM[(size_t)bi * S_ + j] = acc1 + acc2;
}

// ---------------------------------------------------------------------------
// Softmax-weighted average.
// TRANS=0 (beta):  block=b*128+i, softmax_j sim[b,i,:], avg e2, out row bi
// TRANS=1 (alpha): block=b*128+j, softmax_i sim[b,:,j], avg e1, out row 4096+bj
// ---------------------------------------------------------------------------
template <int TRANS>
__global__ __launch_bounds__(128) void k_av(const float* __restrict__ SIM,
                                            const bf16* __restrict__ E,
                                            bf16* __restrict__ OUT) {
    int blk = blockIdx.x;
    int b = blk >> 7;
    int r = blk & (S_ - 1);
    int t = threadIdx.x;
    __shared__ float w[S_];
    __shared__ float red[S_];
    float x;
    if (TRANS == 0) x = SIM[(size_t)blk * S_ + t];
    else            x = SIM[((size_t)b * S_ + t) * S_ + r];
    red[t] = x;
    __syncthreads();
    for (int s = 64; s > 0; s >>= 1) {
        if (t < s) red[t] = fmaxf(red[t], red[t + s]);
        __syncthreads();
    }
    float mx = red[0];
    __syncthreads();
    float ex = expf(x - mx);
    red[t] = ex;
    __syncthreads();
    for (int s = 64; s > 0; s >>= 1) {
        if (t < s) red[t] += red[t + s];
        __syncthreads();
    }
    w[t] = ex / red[0];
    __syncthreads();
    const bf16* Esrc = E + (TRANS == 0 ? (size_t)NT1 * D_ : 0) + (size_t)b * S_ * D_;
    bf16* orow = OUT + (TRANS == 0 ? (size_t)blk * D_ : (size_t)(NT1 + blk) * D_);
    for (int d = t; d < D_; d += 128) {
        float acc = 0.f;
        for (int s = 0; s < S_; ++s) acc += w[s] * ldf(&Esrc[(size_t)s * D_ + d]);
        stf(&orow[d], acc);
    }
}

// ---------------------------------------------------------------------------
// Pool: out[b] = concat(max_i v1, max_j v2, sum_i v1, sum_j v2)  [B,4P] fp32
// ---------------------------------------------------------------------------
__global__ __launch_bounds__(256) void k_pool(const bf16* __restrict__ V,
                                              float* __restrict__ OUT) {
    int b = blockIdx.x;
    int c = threadIdx.x;
    if (c >= P_) return;
    const bf16* v1 = V + (size_t)b * S_ * P_;
    const bf16* v2 = V + (size_t)(NT1 + b * S_) * P_;
    float mx1 = -INFINITY, mx2 = -INFINITY, s1 = 0.f, s2 = 0.f;
    for (int i = 0; i < S_; ++i) {
        float a = ldf(&v1[(size_t)i * P_ + c]);
        mx1 = fmaxf(mx1, a); s1 += a;
        float bb = ldf(&v2[(size_t)i * P_ + c]);
        mx2 = fmaxf(mx2, bb); s2 += bb;
    }
    float* o = OUT + (size_t)b * 4 * P_;
    o[c] = mx1; o[P_ + c] = mx2; o[2 * P_ + c] = s1; o[3 * P_ + c] = s2;
}

// Final cast; output dtype per flag. Non-finite sentinels: 10000 (bf16 mode),
// 20000 (fp32 mode) — diagnostic for which path NaN'd.
__global__ void k_cast(const float* __restrict__ src, void* __restrict__ dst, int n,
                       const int* __restrict__ flag) {
    int f = *flag;
    int i = blockIdx.x * 256 + threadIdx.x;
    if (i < n) {
        float v = src[i];
        if (f) {
            if (!isfinite(v)) v = 20000.f;
            ((float*)dst)[i] = v;
        } else {
            if (!isfinite(v)) v = 10000.f;
            ((bf16*)dst)[i] = __float2bfloat16(v);
        }
    }
}

// Sentinel fill (diagnostic: absmax ~555 => ws_size too small)
__global__ void k_fill(bf16* dst, int n, float v) {
    int i = blockIdx.x * 256 + threadIdx.x;
    if (i < n) dst[i] = __float2bfloat16(v);
}

// ---------------------------------------------------------------------------
// Launch
// ---------------------------------------------------------------------------
extern "C" void kernel_launch(void* const* d_in, const int* in_sizes, int n_in,
                              void* d_out, int out_size, void* d_ws, size_t ws_size,
                              hipStream_t stream) {
    const int* x1 = (const int*)d_in[0];
    const int* x2 = (const int*)d_in[1];
    const void* emb = d_in[2];
    const void *hw1_Wh = d_in[3],  *hw1_bh = d_in[4],  *hw1_Wt = d_in[5],  *hw1_bt = d_in[6];
    const void *hw2_Wh = d_in[7],  *hw2_bh = d_in[8],  *hw2_Wt = d_in[9],  *hw2_bt = d_in[10];
    const void *mul_W1 = d_in[11], *mul_b1 = d_in[12], *mul_W2 = d_in[13], *mul_b2 = d_in[14];
    const void *dist_W1 = d_in[15], *dist_b1 = d_in[16], *dist_W2 = d_in[17], *dist_b2 = d_in[18];
    const void *cmp_W1 = d_in[19], *cmp_b1 = d_in[20], *cmp_W2 = d_in[21], *cmp_b2 = d_in[22];
    const void *chw1_Wh = d_in[23], *chw1_bh = d_in[24], *chw1_Wt = d_in[25], *chw1_bt = d_in[26];
    const void *chw2_Wh = d_in[27], *chw2_bh = d_in[28], *chw2_Wt = d_in[29], *chw2_bt = d_in[30];
    const void *agg_W1 = d_in[31], *agg_b1 = d_in[32], *agg_W2 = d_in[33], *agg_b2 = d_in[34];
    const void *out_W = d_in[35], *out_b = d_in[36];

    // ---- Workspace layout (bf16 intermediates + fp32 SIM/tail + flag) ----
    const size_t nED = (size_t)NT * D_;      // 2,457,600
    const size_t nEP = (size_t)NT * P_;      // 1,638,400
    const size_t nTR = (size_t)B_ * P_ * S_; //   819,200
    const size_t nSIM = (size_t)B_ * S_ * S_;//   524,288
    size_t need = (3 * nED + 2 * nEP) * sizeof(bf16)
                + (nSIM + (size_t)B_ * 4 * P_ + 2 * (size_t)B_ * P_ + B_ * 3) * sizeof(float)
                + 256;
    if (ws_size < need) {   // diagnostic: distinctive sentinel if scratch too small
        k_fill<<<dim3(1), dim3(256), 0, stream>>>((bf16*)d_out, B_ * 3, 555.f);
        return;
    }
    bf16* Eb  = (bf16*)d_ws;           // [NT,D] token states
    bf16* A1b = Eb  + nED;             // scratch: highway h / PT,QT / cmp hidden
    bf16* A2b = A1b + nED;             // scratch: highway t / ATT [NT,D]
    bf16* Pb  = A2b + nED;             // mul projection; later V (compare out)
    bf16* Qb  = Pb  + nEP;             // dist projection
    float* SIM = (float*)(Qb + nEP);   // [B,S,S]
    float* POOL = SIM + nSIM;          // [B,4P]
    float* G1 = POOL + (size_t)B_ * 4 * P_;
    float* G2 = G1 + (size_t)B_ * P_;
    float* FO = G2 + (size_t)B_ * P_;  // [B,C]
    int* flag = (int*)(FO + B_ * 3);
    bf16* PTb = A1b;                   // [B,P,S] overlay
    bf16* QTb = A1b + nTR;
    bf16* Vvb = Pb;                    // compare output overlay
    bf16* Hb  = A1b;                   // cmp hidden overlay [NT,P]

    dim3 blk256(256);
    // 0. dtype detect
    k_detect<<<dim3(1), blk256, 0, stream>>>((const unsigned short*)emb, flag);
    // 1. embed
    k_embed<<<dim3((NT * D_ + 255) / 256), blk256, 0, stream>>>(x1, x2, emb, Eb, flag);

    dim3 gD((D_ + BN - 1) / BN, NT / BM);
    dim3 gP((P_ + BN - 1) / BN, NT / BM);

    // 2-3. embedding highway stack
    k_gemm<0, bf16, bf16><<<gD, blk256, 0, stream>>>(Eb, nullptr, hw1_Wh, hw1_bh, A1b, NT, D_, D_, 1, flag);
    k_gemm<0, bf16, bf16><<<gD, blk256, 0, stream>>>(Eb, nullptr, hw1_Wt, hw1_bt, A2b, NT, D_, D_, 2, flag);
    k_highway<<<dim3((int)((nED + 255) / 256)), blk256, 0, stream>>>(A1b, A2b, Eb, (int)nED);
    k_gemm<0, bf16, bf16><<<gD, blk256, 0, stream>>>(Eb, nullptr, hw2_Wh, hw2_bh, A1b, NT, D_, D_, 1, flag);
    k_gemm<0, bf16, bf16><<<gD, blk256, 0, stream>>>(Eb, nullptr, hw2_Wt, hw2_bt, A2b, NT, D_, D_, 2, flag);
    k_highway<<<dim3((int)((nED + 255) / 256)), blk256, 0, stream>>>(A1b, A2b, Eb, (int)nED);

    // 4. mul ff projection
    k_gemm<0, bf16, bf16><<<gP, blk256, 0, stream>>>(Eb, nullptr, mul_W1, mul_b1, A2b, NT, P_, D_, 1, flag);
    k_gemm<0, bf16, bf16><<<gP, blk256, 0, stream>>>(A2b, nullptr, mul_W2, mul_b2, Pb, NT, P_, P_, 1, flag);
    // 5. dist ff projection
    k_gemm<0, bf16, bf16><<<gP, blk256, 0, stream>>>(Eb, nullptr, dist_W1, dist_b1, A2b, NT, P_, D_, 1, flag);
    k_gemm<0, bf16, bf16><<<gP, blk256, 0, stream>>>(A2b, nullptr, dist_W2, dist_b2, Qb, NT, P_, P_, 1, flag);

    // 6. transpose x2-halves
    k_transpose<<<dim3((int)((nTR + 255) / 256)), blk256, 0, stream>>>(Pb + (size_t)NT1 * P_, PTb);
    k_transpose<<<dim3((int)((nTR + 255) / 256)), blk256, 0, stream>>>(Qb + (size_t)NT1 * P_, QTb);

    // 7. sim
    k_sim<<<dim3(NT1), dim3(128), 0, stream>>>(Pb, Qb, PTb, QTb, SIM);

    // 8. attention: beta -> A2b rows 0..4095, alpha -> A2b rows 4096..8191
    k_av<0><<<dim3(NT1), dim3(128), 0, stream>>>(SIM, Eb, A2b);
    k_av<1><<<dim3(NT1), dim3(128), 0, stream>>>(SIM, Eb, A2b);

    // 9. compare ff (on-the-fly concat)
    k_gemm<1, bf16, bf16><<<gP, blk256, 0, stream>>>(Eb, A2b, cmp_W1, cmp_b1, Hb, NT, P_, 4 * D_, 1, flag);
    k_gemm<0, bf16, bf16><<<gP, blk256, 0, stream>>>(Hb, nullptr, cmp_W2, cmp_b2, Vvb, NT, P_, P_, 1, flag);

    // 10-11. compare highway stack
    k_gemm<0, bf16, bf16><<<gP, blk256, 0, stream>>>(Vvb, nullptr, chw1_Wh, chw1_bh, A1b, NT, P_, P_, 1, flag);
    k_gemm<0, bf16, bf16><<<gP, blk256, 0, stream>>>(Vvb, nullptr, chw1_Wt, chw1_bt, A2b, NT, P_, P_, 2, flag);
    k_highway<<<dim3((int)((nEP + 255) / 256)), blk256, 0, stream>>>(A1b, A2b, Vvb, (int)nEP);
    k_gemm<0, bf16, bf16><<<gP, blk256, 0, stream>>>(Vvb, nullptr, chw2_Wh, chw2_bh, A1b, NT, P_, P_, 1, flag);
    k_gemm<0, bf16, bf16><<<gP, blk256, 0, stream>>>(Vvb, nullptr, chw2_Wt, chw2_bt, A2b, NT, P_, P_, 2, flag);
    k_highway<<<dim3((int)((nEP + 255) / 256)), blk256, 0, stream>>>(A1b, A2b, Vvb, (int)nEP);

    // 12. pool (fp32 out)
    k_pool<<<dim3(B_), blk256, 0, stream>>>(Vvb, POOL);

    // 13-15. aggregate ff + final linear (fp32)
    dim3 g1((P_ + BN - 1) / BN, 1);
    k_gemm<0, float, float><<<g1, blk256, 0, stream>>>(POOL, nullptr, agg_W1, agg_b1, G1, B_, P_, 4 * P_, 1, flag);
    k_gemm<0, float, float><<<g1, blk256, 0, stream>>>(G1, nullptr, agg_W2, agg_b2, G2, B_, P_, P_, 1, flag);
    dim3 g2(1, 1);
    k_gemm<0, float, float><<<g2, blk256, 0, stream>>>(G2, nullptr, out_W, out_b, FO, B_, 3, P_, 0, flag);

    // 16. cast to output dtype (per flag) with non-finite sentinels
    k_cast<<<dim3(1), blk256, 0, stream>>>(FO, d_out, B_ * 3, flag);
}

// Round 4
// 873.732 us; speedup vs baseline: 1.6592x; 1.6592x over previous
//
#include <hip/hip_runtime.h>
#include <hip/hip_bf16.h>
#include <math.h>

// Problem constants
#define B_   32
#define S_   128
#define V_   30000
#define D_   300
#define P_   200
#define NT   8192         // 2*B*S token rows: x1 rows 0..4095, x2 rows 4096..8191
#define NT1  4096

typedef __hip_bfloat16 bf16;
typedef __attribute__((ext_vector_type(8))) __bf16 bf16x8;
typedef __attribute__((ext_vector_type(4))) float f32x4;

__device__ __forceinline__ float b2f(bf16 v) { return __bfloat162float(v); }
__device__ __forceinline__ short f2s(float v) { bf16 h = __float2bfloat16(v); return *(short*)&h; }

// ---------------------------------------------------------------------------
// Fused weight conversion: fp32 [K][N] (optionally two sources concat along N)
// -> bf16 WT[Npad][Kpad], WT[n*Kpad+k] = W[k][n], zero pads. 9 matrices, 1 dispatch.
// ---------------------------------------------------------------------------
struct ConvTable {
    const float* W1[9]; const float* W2[9]; bf16* dst[9];
    int K[9], N1[9], N2[9], Kpad[9];
    unsigned long long base[9]; unsigned long long total;
};

__global__ void k_convw(ConvTable T) {
    unsigned long long idx = (unsigned long long)blockIdx.x * 256 + threadIdx.x;
    if (idx >= T.total) return;
    int e = 0;
#pragma unroll
    for (int i = 1; i < 9; ++i) if (idx >= T.base[i]) e = i;
    unsigned long long local = idx - T.base[e];
    int Kpad = T.Kpad[e];
    int n = (int)(local / Kpad);
    int k = (int)(local - (unsigned long long)n * Kpad);
    float v = 0.f;
    if (k < T.K[e]) {
        if (n < T.N1[e]) v = T.W1[e][(size_t)k * T.N1[e] + n];
        else if (n < T.N1[e] + T.N2[e]) v = T.W2[e][(size_t)k * T.N2[e] + (n - T.N1[e])];
    }
    T.dst[e][local] = __float2bfloat16(v);
}

// ---------------------------------------------------------------------------
// Embedding gather: fp32 emb -> bf16 E
// ---------------------------------------------------------------------------
__global__ void k_embed(const int* __restrict__ x1, const int* __restrict__ x2,
                        const float* __restrict__ emb, bf16* __restrict__ E) {
    int idx = blockIdx.x * 256 + threadIdx.x;
    if (idx >= NT * D_) return;
    int r = idx / D_;
    int d = idx - r * D_;
    int tok = (r < NT1) ? x1[r] : x2[r - NT1];
    if ((unsigned)tok >= (unsigned)V_) tok = 0;
    E[idx] = __float2bfloat16(emb[(size_t)tok * D_ + d]);
}

// ---------------------------------------------------------------------------
// MFMA GEMM: C[gm, col] = act(A[M x K] @ W + bias), A/C bf16, fp32 accum.
// W given as WT[Npad][Kpad] bf16 (transposed, zero-padded).
// Columns [0,N1) use bias1/act1; [N1,Ntot) use bias2/act2 (combined GEMMs).
// Block 128x64, 4 waves each 32x64 via 16x16x32 MFMA. M must be mult of 128.
// CAT=1: logical A = concat([A, A2, A-A2, A*A2]) along K (segments of D_=300).
// act: 0=none, 1=relu, 2=sigmoid.
// ---------------------------------------------------------------------------
#define TM 128
#define TN 64
#define TK 32
#define TKP 40

template <int CAT>
__global__ __launch_bounds__(256) void k_mfma_gemm(
    const bf16* __restrict__ A, int lda, const bf16* __restrict__ A2,
    const bf16* __restrict__ WT, int Kpad, int K,
    bf16* __restrict__ C, int ldc, int Ntot, int N1,
    const float* __restrict__ bias1, const float* __restrict__ bias2,
    int act1, int act2)
{
    __shared__ short As[TM][TKP];
    __shared__ short Bs[TN][TKP];
    int tid = threadIdx.x;
    int w = tid >> 6, lane = tid & 63, quad = lane >> 4, l16 = lane & 15;
    int bm = blockIdx.y * TM;
    int bn = blockIdx.x * TN;

    // staging roles
    int am = tid >> 1;              // 0..127 (A row in tile)
    int ak = (tid & 1) * 16;        // 0/16   (A k-chunk)
    int bnl = tid >> 2;             // 0..63  (B n in tile)
    int bk = (tid & 3) * 8;         // 0/8/16/24 (B k-chunk)
    const int gm_a = bm + am;
    const short* Ash = (const short*)A;

    f32x4 acc[2][4];
#pragma unroll
    for (int i = 0; i < 2; ++i)
#pragma unroll
        for (int j = 0; j < 4; ++j)
#pragma unroll
            for (int r = 0; r < 4; ++r) acc[i][j][r] = 0.f;

    for (int k0 = 0; k0 < Kpad; k0 += TK) {
        // ---- stage A tile (128 x 32), guarded vs actual K, zero-padded
        int kbase = k0 + ak;
        if (CAT == 0) {
            if (kbase + 16 <= K) {
                const short4* p = (const short4*)(Ash + (size_t)gm_a * lda + kbase);
                short4 v0 = p[0], v1 = p[1], v2 = p[2], v3 = p[3];
                short4* q = (short4*)&As[am][ak];
                q[0] = v0; q[1] = v1; q[2] = v2; q[3] = v3;
            } else {
#pragma unroll
                for (int i = 0; i < 16; ++i) {
                    int k = kbase + i;
                    As[am][ak + i] = (k < K) ? Ash[(size_t)gm_a * lda + k] : (short)0;
                }
            }
        } else {
#pragma unroll
            for (int i = 0; i < 16; ++i) {
                int k = kbase + i;
                float v = 0.f;
                if (k < 4 * D_) {
                    int sel = k / D_;
                    int kc = k - sel * D_;
                    float e = b2f(A[(size_t)gm_a * D_ + kc]);
                    float t = b2f(A2[(size_t)gm_a * D_ + kc]);
                    v = (sel == 0) ? e : (sel == 1) ? t : (sel == 2) ? (e - t) : (e * t);
                }
                As[am][ak + i] = f2s(v);
            }
        }
        // ---- stage B tile (64 x 32), WT pre-padded: no guards
        {
            const short4* p = (const short4*)((const short*)WT + (size_t)(bn + bnl) * Kpad + k0 + bk);
            short4 v0 = p[0], v1 = p[1];
            short4* q = (short4*)&Bs[bnl][bk];
            q[0] = v0; q[1] = v1;
        }
        __syncthreads();
        // ---- fragments + MFMA
        {
            bf16x8 a[2], b[4];
#pragma unroll
            for (int mt = 0; mt < 2; ++mt)
                a[mt] = *(const bf16x8*)&As[w * 32 + mt * 16 + l16][quad * 8];
#pragma unroll
            for (int nt = 0; nt < 4; ++nt)
                b[nt] = *(const bf16x8*)&Bs[nt * 16 + l16][quad * 8];
#pragma unroll
            for (int mt = 0; mt < 2; ++mt)
#pragma unroll
                for (int nt = 0; nt < 4; ++nt)
                    acc[mt][nt] = __builtin_amdgcn_mfma_f32_16x16x32_bf16(a[mt], b[nt], acc[mt][nt], 0, 0, 0);
        }
        __syncthreads();
    }
    // ---- epilogue: bias + activation per column segment, bf16 store
#pragma unroll
    for (int mt = 0; mt < 2; ++mt) {
        int row = bm + w * 32 + mt * 16 + quad * 4;
#pragma unroll
        for (int nt = 0; nt < 4; ++nt) {
            int col = bn + nt * 16 + l16;
            if (col >= Ntot) continue;
            float bv; int act;
            if (col < N1) { bv = bias1[col]; act = act1; }
            else          { bv = bias2[col - N1]; act = act2; }
#pragma unroll
            for (int r = 0; r < 4; ++r) {
                float v = acc[mt][nt][r] + bv;
                if (act == 1) v = fmaxf(v, 0.f);
                else if (act == 2) v = 1.f / (1.f + expf(-v));
                C[(size_t)(row + r) * ldc + col] = __float2bfloat16(v);
            }
        }
    }
}

// ---------------------------------------------------------------------------
// Highway combine from packed h|t buffer: X = t*h + (1-t)*X
// HT[m*ldht + d] = h, HT[m*ldht + nseg + d] = t; X is [NT, width] contiguous.
// ---------------------------------------------------------------------------
__global__ void k_highway2(const bf16* __restrict__ HT, int ldht, int nseg,
                           bf16* __restrict__ X, int width) {
    int idx = blockIdx.x * 256 + threadIdx.x;
    if (idx >= NT * width) return;
    int m = idx / width, d = idx - m * width;
    float h = b2f(HT[(size_t)m * ldht + d]);
    float t = b2f(HT[(size_t)m * ldht + nseg + d]);
    float x = b2f(X[idx]);
    X[idx] = __float2bfloat16(t * h + (1.f - t) * x);
}

// ---------------------------------------------------------------------------
// Transpose x2-half of [NT,P] into [B,P,S]
// ---------------------------------------------------------------------------
__global__ void k_transpose(const bf16* __restrict__ src, bf16* __restrict__ dst) {
    int idx = blockIdx.x * 256 + threadIdx.x;
    if (idx >= B_ * P_ * S_) return;
    int j = idx & (S_ - 1);
    int rest = idx >> 7;
    int p = rest % P_;
    int b = rest / P_;
    dst[idx] = src[((size_t)(b * S_ + j)) * P_ + p];
}

// ---------------------------------------------------------------------------
// sim[b,i,j] = dot_p(p1,p2) + sum_p 1/(1+|q1-q2|); block=b*128+i, thread=j
// ---------------------------------------------------------------------------
__global__ __launch_bounds__(128) void k_sim(const bf16* __restrict__ Pmat,
                                             const bf16* __restrict__ Qmat,
                                             const bf16* __restrict__ PT,
                                             const bf16* __restrict__ QT,
                                             float* __restrict__ SIM) {
    int bi = blockIdx.x;
    int b = bi >> 7;
    int j = threadIdx.x;
    __shared__ float p1[P_], q1[P_];
    const bf16* prow = Pmat + (size_t)bi * P_;
    const bf16* qrow = Qmat + (size_t)bi * P_;
    for (int t = j; t < P_; t += 128) { p1[t] = b2f(prow[t]); q1[t] = b2f(qrow[t]); }
    __syncthreads();
    const bf16* pt = PT + (size_t)b * P_ * S_;
    const bf16* qt = QT + (size_t)b * P_ * S_;
    float acc1 = 0.f, acc2 = 0.f;
    for (int p = 0; p < P_; ++p) {
        float v = b2f(pt[p * S_ + j]);
        float u = b2f(qt[p * S_ + j]);
        acc1 += p1[p] * v;
        acc2 += 1.f / (1.f + fabsf(q1[p] - u));
    }
    SIM[(size_t)bi * S_ + j] = acc1 + acc2;
}

// ---------------------------------------------------------------------------
// Softmax-weighted average (proven in round 3).
// ---------------------------------------------------------------------------
template <int TRANS>
__global__ __launch_bounds__(128) void k_av(const float* __restrict__ SIM,
                                            const bf16* __restrict__ E,
                                            bf16* __restrict__ OUT) {
    int blk = blockIdx.x;
    int b = blk >> 7;
    int r = blk & (S_ - 1);
    int t = threadIdx.x;
    __shared__ float w[S_];
    __shared__ float red[S_];
    float x;
    if (TRANS == 0) x = SIM[(size_t)blk * S_ + t];
    else            x = SIM[((size_t)b * S_ + t) * S_ + r];
    red[t] = x;
    __syncthreads();
    for (int s = 64; s > 0; s >>= 1) {
        if (t < s) red[t] = fmaxf(red[t], red[t + s]);
        __syncthreads();
    }
    float mx = red[0];
    __syncthreads();
    float ex = expf(x - mx);
    red[t] = ex;
    __syncthreads();
    for (int s = 64; s > 0; s >>= 1) {
        if (t < s) red[t] += red[t + s];
        __syncthreads();
    }
    w[t] = ex / red[0];
    __syncthreads();
    const bf16* Esrc = E + (TRANS == 0 ? (size_t)NT1 * D_ : 0) + (size_t)b * S_ * D_;
    bf16* orow = OUT + (TRANS == 0 ? (size_t)blk * D_ : (size_t)(NT1 + blk) * D_);
    for (int d = t; d < D_; d += 128) {
        float acc = 0.f;
        for (int s = 0; s < S_; ++s) acc += w[s] * b2f(Esrc[(size_t)s * D_ + d]);
        orow[d] = __float2bfloat16(acc);
    }
}

// ---------------------------------------------------------------------------
// Pool: out[b] = concat(max_i v1, max_j v2, sum_i v1, sum_j v2)  [B,4P] fp32
// ---------------------------------------------------------------------------
__global__ __launch_bounds__(256) void k_pool(const bf16* __restrict__ V,
                                              float* __restrict__ OUT) {
    int b = blockIdx.x;
    int c = threadIdx.x;
    if (c >= P_) return;
    const bf16* v1 = V + (size_t)b * S_ * P_;
    const bf16* v2 = V + (size_t)(NT1 + b * S_) * P_;
    float mx1 = -INFINITY, mx2 = -INFINITY, s1 = 0.f, s2 = 0.f;
    for (int i = 0; i < S_; ++i) {
        float a = b2f(v1[(size_t)i * P_ + c]);
        mx1 = fmaxf(mx1, a); s1 += a;
        float bb = b2f(v2[(size_t)i * P_ + c]);
        mx2 = fmaxf(mx2, bb); s2 += bb;
    }
    float* o = OUT + (size_t)b * 4 * P_;
    o[c] = mx1; o[P_ + c] = mx2; o[2 * P_ + c] = s1; o[3 * P_ + c] = s2;
}

// ---------------------------------------------------------------------------
// Small fp32 SIMD GEMM for the M=32 tail: C = act(A@W + bias)
// ---------------------------------------------------------------------------
#define SBM 64
#define SBN 64
#define SBK 16
__global__ __launch_bounds__(256) void k_gemm_f32(
    const float* __restrict__ A, const float* __restrict__ W,
    const float* __restrict__ bias, float* __restrict__ C,
    int M, int N, int K, int act) {
    __shared__ float As[SBK][SBM + 1];
    __shared__ float Ws[SBK][SBN + 1];
    int tid = threadIdx.x;
    int bm = blockIdx.y * SBM;
    int bn = blockIdx.x * SBN;
    int tx = tid & 15, ty = tid >> 4;
    float acc[4][4] = {};
    for (int k0 = 0; k0 < K; k0 += SBK) {
#pragma unroll
        for (int l = 0; l < 4; ++l) {
            int idx = tid + l * 256;
            int m = idx >> 4, kk = idx & 15;
            int gm = bm + m, gk = k0 + kk;
            As[kk][m] = (gm < M && gk < K) ? A[(size_t)gm * K + gk] : 0.f;
        }
#pragma unroll
        for (int l = 0; l < 4; ++l) {
            int idx = tid + l * 256;
            int kk = idx >> 6, n = idx & 63;
            int gk = k0 + kk, gn = bn + n;
            Ws[kk][n] = (gk < K && gn < N) ? W[(size_t)gk * N + gn] : 0.f;
        }
        __syncthreads();
#pragma unroll
        for (int kk = 0; kk < SBK; ++kk) {
            float a[4], w[4];
#pragma unroll
            for (int i = 0; i < 4; ++i) a[i] = As[kk][ty * 4 + i];
#pragma unroll
            for (int j = 0; j < 4; ++j) w[j] = Ws[kk][tx * 4 + j];
#pragma unroll
            for (int i = 0; i < 4; ++i)
#pragma unroll
                for (int j = 0; j < 4; ++j) acc[i][j] += a[i] * w[j];
        }
        __syncthreads();
    }
#pragma unroll
    for (int i = 0; i < 4; ++i) {
        int gm = bm + ty * 4 + i;
        if (gm >= M) continue;
#pragma unroll
        for (int j = 0; j < 4; ++j) {
            int gn = bn + tx * 4 + j;
            if (gn >= N) continue;
            float v = acc[i][j] + bias[gn];
            if (act == 1) v = fmaxf(v, 0.f);
            else if (act == 2) v = 1.f / (1.f + expf(-v));
            C[(size_t)gm * N + gn] = v;
        }
    }
}

// Sentinel fill (diagnostic: absmax ~555 => ws_size too small)
__global__ void k_fillf(float* dst, int n, float v) {
    int i = blockIdx.x * 256 + threadIdx.x;
    if (i < n) dst[i] = v;
}

// ---------------------------------------------------------------------------
// Launch
// ---------------------------------------------------------------------------
extern "C" void kernel_launch(void* const* d_in, const int* in_sizes, int n_in,
                              void* d_out, int out_size, void* d_ws, size_t ws_size,
                              hipStream_t stream) {
    const int* x1 = (const int*)d_in[0];
    const int* x2 = (const int*)d_in[1];
    const float* emb = (const float*)d_in[2];
    const float *hw1_Wh = (const float*)d_in[3],  *hw1_bh = (const float*)d_in[4];
    const float *hw1_Wt = (const float*)d_in[5],  *hw1_bt = (const float*)d_in[6];
    const float *hw2_Wh = (const float*)d_in[7],  *hw2_bh = (const float*)d_in[8];
    const float *hw2_Wt = (const float*)d_in[9],  *hw2_bt = (const float*)d_in[10];
    const float *mul_W1 = (const float*)d_in[11], *mul_b1 = (const float*)d_in[12];
    const float *mul_W2 = (const float*)d_in[13], *mul_b2 = (const float*)d_in[14];
    const float *dist_W1 = (const float*)d_in[15], *dist_b1 = (const float*)d_in[16];
    const float *dist_W2 = (const float*)d_in[17], *dist_b2 = (const float*)d_in[18];
    const float *cmp_W1 = (const float*)d_in[19], *cmp_b1 = (const float*)d_in[20];
    const float *cmp_W2 = (const float*)d_in[21], *cmp_b2 = (const float*)d_in[22];
    const float *chw1_Wh = (const float*)d_in[23], *chw1_bh = (const float*)d_in[24];
    const float *chw1_Wt = (const float*)d_in[25], *chw1_bt = (const float*)d_in[26];
    const float *chw2_Wh = (const float*)d_in[27], *chw2_bh = (const float*)d_in[28];
    const float *chw2_Wt = (const float*)d_in[29], *chw2_bt = (const float*)d_in[30];
    const float *agg_W1 = (const float*)d_in[31], *agg_b1 = (const float*)d_in[32];
    const float *agg_W2 = (const float*)d_in[33], *agg_b2 = (const float*)d_in[34];
    const float *out_W = (const float*)d_in[35], *out_b = (const float*)d_in[36];

    // ---- Workspace layout (elems) ----
    const size_t nED = (size_t)NT * D_;        // 2,457,600
    const size_t nEP = (size_t)NT * P_;        // 1,638,400
    const size_t nCht = (size_t)NT * 600;      // 4,915,200
    const size_t nTR = (size_t)B_ * P_ * S_;   //   819,200
    const size_t nWT = 1236992;                // converted weights total
    size_t bf16_elems = 2 * nED + 2 * nEP + nCht + nWT;
    size_t f32_elems = (size_t)B_ * 4 * P_ + 2 * (size_t)B_ * P_;
    size_t need = bf16_elems * 2 + f32_elems * 4 + 64;
    if (ws_size < need) {
        k_fillf<<<dim3(1), dim3(256), 0, stream>>>((float*)d_out, B_ * 3, 555.f);
        return;
    }
    bf16* Eb  = (bf16*)d_ws;            // [NT,300]
    bf16* A2b = Eb + nED;               // [NT,300] ATT
    bf16* Pb  = A2b + nED;              // [NT,200] mul proj -> V
    bf16* Qb  = Pb + nEP;               // [NT,200] dist proj
    bf16* Cht = Qb + nEP;               // [NT,600] packed h|t / hidden / PT/QT/SIM
    bf16* WTp = Cht + nCht;             // converted weights pool
    float* POOL = (float*)(WTp + nWT);  // [B,4P]
    float* G1 = POOL + (size_t)B_ * 4 * P_;
    float* G2 = G1 + (size_t)B_ * P_;
    // overlays inside Cht:
    bf16* PTb = Cht;
    bf16* QTb = Cht + nTR;
    float* SIM = (float*)(Cht + 2 * nTR);   // byte offset 3,276,800: 16B-aligned

    // converted-weight sub-buffers (elems)
    bf16* WT_hw1 = WTp + 0;        // 640x320
    bf16* WT_hw2 = WTp + 204800;   // 640x320
    bf16* WT_md  = WTp + 409600;   // 448x320 (mul_W1 | dist_W1)
    bf16* WT_m2  = WTp + 552960;   // 256x224
    bf16* WT_d2  = WTp + 610304;   // 256x224
    bf16* WT_c1  = WTp + 667648;   // 256x1216
    bf16* WT_c2  = WTp + 978944;   // 256x224
    bf16* WT_ch1 = WTp + 1036288;  // 448x224 (chw1_Wh | chw1_Wt)
    bf16* WT_ch2 = WTp + 1136640;  // 448x224

    dim3 blk256(256);

    // 0. fused weight conversion (1 dispatch)
    ConvTable T;
    const float* s1[9] = {hw1_Wh, hw2_Wh, mul_W1, mul_W2, dist_W2, cmp_W1, cmp_W2, chw1_Wh, chw2_Wh};
    const float* s2[9] = {hw1_Wt, hw2_Wt, dist_W1, nullptr, nullptr, nullptr, nullptr, chw1_Wt, chw2_Wt};
    bf16* dsts[9] = {WT_hw1, WT_hw2, WT_md, WT_m2, WT_d2, WT_c1, WT_c2, WT_ch1, WT_ch2};
    int Ks[9]  = {300, 300, 300, 200, 200, 1200, 200, 200, 200};
    int N1s[9] = {300, 300, 200, 200, 200, 200, 200, 200, 200};
    int N2s[9] = {300, 300, 200, 0, 0, 0, 0, 200, 200};
    int Kps[9] = {320, 320, 320, 224, 224, 1216, 224, 224, 224};
    int Nps[9] = {640, 640, 448, 256, 256, 256, 256, 448, 448};
    unsigned long long base = 0;
    for (int i = 0; i < 9; ++i) {
        T.W1[i] = s1[i]; T.W2[i] = s2[i]; T.dst[i] = dsts[i];
        T.K[i] = Ks[i]; T.N1[i] = N1s[i]; T.N2[i] = N2s[i]; T.Kpad[i] = Kps[i];
        T.base[i] = base;
        base += (unsigned long long)Kps[i] * Nps[i];
    }
    T.total = base;   // 1,236,992
    k_convw<<<dim3((unsigned)((base + 255) / 256)), blk256, 0, stream>>>(T);

    // 1. embed
    k_embed<<<dim3((NT * D_ + 255) / 256), blk256, 0, stream>>>(x1, x2, emb, Eb);

    const dim3 gRows(0, 0);
    int hwyD = (NT * D_ + 255) / 256, hwyP = (NT * P_ + 255) / 256;

    // 2-3. embedding highway stack: combined h|t GEMM (N=600) + combine
    k_mfma_gemm<0><<<dim3(10, 64), blk256, 0, stream>>>(Eb, 300, nullptr, WT_hw1, 320, 300,
        Cht, 600, 600, 300, hw1_bh, hw1_bt, 1, 2);
    k_highway2<<<dim3(hwyD), blk256, 0, stream>>>(Cht, 600, 300, Eb, 300);
    k_mfma_gemm<0><<<dim3(10, 64), blk256, 0, stream>>>(Eb, 300, nullptr, WT_hw2, 320, 300,
        Cht, 600, 600, 300, hw2_bh, hw2_bt, 1, 2);
    k_highway2<<<dim3(hwyD), blk256, 0, stream>>>(Cht, 600, 300, Eb, 300);

    // 4-5. mul+dist W1 combined (N=400) -> Cht; then W2s -> Pb, Qb
    k_mfma_gemm<0><<<dim3(7, 64), blk256, 0, stream>>>(Eb, 300, nullptr, WT_md, 320, 300,
        Cht, 400, 400, 200, mul_b1, dist_b1, 1, 1);
    k_mfma_gemm<0><<<dim3(4, 64), blk256, 0, stream>>>(Cht, 400, nullptr, WT_m2, 224, 200,
        Pb, 200, 200, 200, mul_b2, mul_b2, 1, 1);
    k_mfma_gemm<0><<<dim3(4, 64), blk256, 0, stream>>>(Cht + 200, 400, nullptr, WT_d2, 224, 200,
        Qb, 200, 200, 200, dist_b2, dist_b2, 1, 1);

    // 6. transpose x2-halves into Cht overlay
    int nTRb = (int)((nTR + 255) / 256);
    k_transpose<<<dim3(nTRb), blk256, 0, stream>>>(Pb + (size_t)NT1 * P_, PTb);
    k_transpose<<<dim3(nTRb), blk256, 0, stream>>>(Qb + (size_t)NT1 * P_, QTb);

    // 7. sim
    k_sim<<<dim3(NT1), dim3(128), 0, stream>>>(Pb, Qb, PTb, QTb, SIM);

    // 8. attention: beta -> A2b rows 0..4095, alpha -> rows 4096..8191
    k_av<0><<<dim3(NT1), dim3(128), 0, stream>>>(SIM, Eb, A2b);
    k_av<1><<<dim3(NT1), dim3(128), 0, stream>>>(SIM, Eb, A2b);

    // 9. compare ff: CAT GEMM (K=1200) -> hidden in Cht; W2 -> Vv (=Pb)
    k_mfma_gemm<1><<<dim3(4, 64), blk256, 0, stream>>>(Eb, 300, A2b, WT_c1, 1216, 1200,
        Cht, 200, 200, 200, cmp_b1, cmp_b1, 1, 1);
    k_mfma_gemm<0><<<dim3(4, 64), blk256, 0, stream>>>(Cht, 200, nullptr, WT_c2, 224, 200,
        Pb, 200, 200, 200, cmp_b2, cmp_b2, 1, 1);

    // 10-11. compare highway stack (combined N=400 GEMMs)
    k_mfma_gemm<0><<<dim3(7, 64), blk256, 0, stream>>>(Pb, 200, nullptr, WT_ch1, 224, 200,
        Cht, 400, 400, 200, chw1_bh, chw1_bt, 1, 2);
    k_highway2<<<dim3(hwyP), blk256, 0, stream>>>(Cht, 400, 200, Pb, 200);
    k_mfma_gemm<0><<<dim3(7, 64), blk256, 0, stream>>>(Pb, 200, nullptr, WT_ch2, 224, 200,
        Cht, 400, 400, 200, chw2_bh, chw2_bt, 1, 2);
    k_highway2<<<dim3(hwyP), blk256, 0, stream>>>(Cht, 400, 200, Pb, 200);

    // 12. pool
    k_pool<<<dim3(B_), blk256, 0, stream>>>(Pb, POOL);

    // 13-15. aggregate ff + final linear (fp32 SIMD, M=32); last writes d_out
    k_gemm_f32<<<dim3(4, 1), blk256, 0, stream>>>(POOL, agg_W1, agg_b1, G1, B_, P_, 4 * P_, 1);
    k_gemm_f32<<<dim3(4, 1), blk256, 0, stream>>>(G1, agg_W2, agg_b2, G2, B_, P_, P_, 1);
    k_gemm_f32<<<dim3(1, 1), blk256, 0, stream>>>(G2, out_W, out_b, (float*)d_out, B_, 3, P_, 0);
}

// Round 5
// 669.871 us; speedup vs baseline: 2.1641x; 1.3043x over previous
//
#include <hip/hip_runtime.h>
#include <hip/hip_bf16.h>
#include <math.h>

// Problem constants
#define B_   32
#define S_   128
#define V_   30000
#define D_   300
#define P_   200
#define NT   8192         // 2*B*S token rows: x1 rows 0..4095, x2 rows 4096..8191
#define NT1  4096

typedef __hip_bfloat16 bf16;
typedef __attribute__((ext_vector_type(8))) __bf16 bf16x8;
typedef __attribute__((ext_vector_type(4))) float f32x4;

__device__ __forceinline__ float b2f(bf16 v) { return __bfloat162float(v); }
__device__ __forceinline__ short f2s(float v) { bf16 h = __float2bfloat16(v); return *(short*)&h; }
__device__ __forceinline__ float s2f(short s) { bf16 h; *(short*)&h = s; return __bfloat162float(h); }

// ---------------------------------------------------------------------------
// Fused weight conversion: fp32 [K][N] (optionally two sources concat along N)
// -> bf16 WT[Npad][Kpad], WT[n*Kpad+k] = W[k][n], zero pads (Npad mult of 128
// so B staging needs no guards anywhere).
// ---------------------------------------------------------------------------
struct ConvTable {
    const float* W1[9]; const float* W2[9]; bf16* dst[9];
    int K[9], N1[9], N2[9], Kpad[9];
    unsigned long long base[9]; unsigned long long total;
};

__global__ void k_convw(ConvTable T) {
    unsigned long long idx = (unsigned long long)blockIdx.x * 256 + threadIdx.x;
    if (idx >= T.total) return;
    int e = 0;
#pragma unroll
    for (int i = 1; i < 9; ++i) if (idx >= T.base[i]) e = i;
    unsigned long long local = idx - T.base[e];
    int Kpad = T.Kpad[e];
    int n = (int)(local / Kpad);
    int k = (int)(local - (unsigned long long)n * Kpad);
    float v = 0.f;
    if (k < T.K[e]) {
        if (n < T.N1[e]) v = T.W1[e][(size_t)k * T.N1[e] + n];
        else if (n < T.N1[e] + T.N2[e]) v = T.W2[e][(size_t)k * T.N2[e] + (n - T.N1[e])];
    }
    T.dst[e][local] = __float2bfloat16(v);
}

// ---------------------------------------------------------------------------
// Embedding gather: fp32 emb -> bf16 E
// ---------------------------------------------------------------------------
__global__ void k_embed(const int* __restrict__ x1, const int* __restrict__ x2,
                        const float* __restrict__ emb, bf16* __restrict__ E) {
    int idx = blockIdx.x * 256 + threadIdx.x;
    if (idx >= NT * D_) return;
    int r = idx / D_;
    int d = idx - r * D_;
    int tok = (r < NT1) ? x1[r] : x2[r - NT1];
    if ((unsigned)tok >= (unsigned)V_) tok = 0;
    E[idx] = __float2bfloat16(emb[(size_t)tok * D_ + d]);
}

// ---------------------------------------------------------------------------
// Dense concat features: CatB[m, 0:1216] = [E, ATT, E-ATT, E*ATT, 0-pad]
// 4 elems (8B) per thread; 300 = 75*4 so chunks never straddle segments.
// ---------------------------------------------------------------------------
__global__ void k_cat(const bf16* __restrict__ E, const bf16* __restrict__ ATT,
                      bf16* __restrict__ CatB) {
    int idx = blockIdx.x * 256 + threadIdx.x;   // 4-elem chunk id
    const int total = NT * 304;                 // 1216/4 chunks per row
    if (idx >= total) return;
    int m = idx / 304;
    int c = idx - m * 304;
    short4 out = {0, 0, 0, 0};
    if (c < 300) {
        int sel = c / 75;
        int kc = (c - sel * 75) * 4;
        short4 ev = *(const short4*)((const short*)E + (size_t)m * D_ + kc);
        short4 av = *(const short4*)((const short*)ATT + (size_t)m * D_ + kc);
        const short* ep = (const short*)&ev;
        const short* ap = (const short*)&av;
        short* op = (short*)&out;
#pragma unroll
        for (int i = 0; i < 4; ++i) {
            float e = s2f(ep[i]), a = s2f(ap[i]);
            float v = (sel == 0) ? e : (sel == 1) ? a : (sel == 2) ? (e - a) : (e * a);
            op[i] = f2s(v);
        }
    }
    *(short4*)((short*)CatB + (size_t)m * 1216 + c * 4) = out;
}

// ---------------------------------------------------------------------------
// MFMA GEMM: C[row, col] = act(A[M x K] @ W + bias), A/C bf16, fp32 accum.
// W as WT[Npad][Kpad] bf16 (transposed, zero-padded, Npad mult of 128).
// Block tile 64(M) x 128(N): 4 waves in 2x2, each 32x64 via 16x16x32 MFMA.
// Columns [0,N1) use bias1/act1; [N1,Ntot) use bias2/act2 (combined GEMMs).
// M must be mult of 64. act: 0=none, 1=relu, 2=sigmoid.
// ---------------------------------------------------------------------------
#define TM 64
#define TN 128
#define TK 32
#define TKP 40

__global__ __launch_bounds__(256) void k_mfma_gemm(
    const bf16* __restrict__ A, int lda,
    const bf16* __restrict__ WT, int Kpad, int K,
    bf16* __restrict__ C, int ldc, int Ntot, int N1,
    const float* __restrict__ bias1, const float* __restrict__ bias2,
    int act1, int act2)
{
    __shared__ short As[TM][TKP];
    __shared__ short Bs[TN][TKP];
    int tid = threadIdx.x;
    int w = tid >> 6, lane = tid & 63, quad = lane >> 4, l16 = lane & 15;
    int bm = blockIdx.y * TM;
    int bn = blockIdx.x * TN;
    int wr = (w & 1) * 32;        // wave row offset in tile
    int wc = (w >> 1) * 64;       // wave col offset in tile

    // staging roles (full-cache-line coalesced)
    int ar = tid >> 2;            // 0..63 : A row in tile
    int ac = (tid & 3) * 8;       // 0/8/16/24 : A k-offset (8 elems = 16B)
    int br = tid >> 1;            // 0..127 : B n-row in tile
    int bc = (tid & 1) * 16;      // 0/16 : B k-offset (16 elems = 32B)
    const short* Ash = (const short*)A;
    const short* Wsh = (const short*)WT;

    f32x4 acc[2][4];
#pragma unroll
    for (int i = 0; i < 2; ++i)
#pragma unroll
        for (int j = 0; j < 4; ++j)
#pragma unroll
            for (int r = 0; r < 4; ++r) acc[i][j][r] = 0.f;

    for (int k0 = 0; k0 < Kpad; k0 += TK) {
        // ---- A tile (64 x 32): 4 lanes cover one 64B row-chunk
        {
            int k = k0 + ac;
            const short* src = Ash + (size_t)(bm + ar) * lda + k;
            if (k + 8 <= K) {
                short4 v0 = ((const short4*)src)[0];
                short4 v1 = ((const short4*)src)[1];
                *(short4*)&As[ar][ac] = v0;
                *(short4*)&As[ar][ac + 4] = v1;
            } else {
#pragma unroll
                for (int i = 0; i < 8; ++i)
                    As[ar][ac + i] = (k + i < K) ? src[i] : (short)0;
            }
        }
        // ---- B tile (128 x 32): WT pre-padded, no guards
        {
            const short* src = Wsh + (size_t)(bn + br) * Kpad + k0 + bc;
            short4 v0 = ((const short4*)src)[0];
            short4 v1 = ((const short4*)src)[1];
            short4 v2 = ((const short4*)src)[2];
            short4 v3 = ((const short4*)src)[3];
            short4* q = (short4*)&Bs[br][bc];
            q[0] = v0; q[1] = v1; q[2] = v2; q[3] = v3;
        }
        __syncthreads();
        {
            bf16x8 a[2], b[4];
#pragma unroll
            for (int mt = 0; mt < 2; ++mt)
                a[mt] = *(const bf16x8*)&As[wr + mt * 16 + l16][quad * 8];
#pragma unroll
            for (int nt = 0; nt < 4; ++nt)
                b[nt] = *(const bf16x8*)&Bs[wc + nt * 16 + l16][quad * 8];
#pragma unroll
            for (int mt = 0; mt < 2; ++mt)
#pragma unroll
                for (int nt = 0; nt < 4; ++nt)
                    acc[mt][nt] = __builtin_amdgcn_mfma_f32_16x16x32_bf16(a[mt], b[nt], acc[mt][nt], 0, 0, 0);
        }
        __syncthreads();
    }
    // ---- epilogue: bias + activation per column segment, bf16 store
#pragma unroll
    for (int mt = 0; mt < 2; ++mt) {
        int row = bm + wr + mt * 16 + quad * 4;
#pragma unroll
        for (int nt = 0; nt < 4; ++nt) {
            int col = bn + wc + nt * 16 + l16;
            if (col >= Ntot) continue;
            float bv; int act;
            if (col < N1) { bv = bias1[col]; act = act1; }
            else          { bv = bias2[col - N1]; act = act2; }
#pragma unroll
            for (int r = 0; r < 4; ++r) {
                float v = acc[mt][nt][r] + bv;
                if (act == 1) v = fmaxf(v, 0.f);
                else if (act == 2) v = 1.f / (1.f + expf(-v));
                C[(size_t)(row + r) * ldc + col] = __float2bfloat16(v);
            }
        }
    }
}

// ---------------------------------------------------------------------------
// Highway combine from packed h|t buffer: X = t*h + (1-t)*X
// ---------------------------------------------------------------------------
__global__ void k_highway2(const bf16* __restrict__ HT, int ldht, int nseg,
                           bf16* __restrict__ X, int width) {
    int idx = blockIdx.x * 256 + threadIdx.x;
    if (idx >= NT * width) return;
    int m = idx / width, d = idx - m * width;
    float h = b2f(HT[(size_t)m * ldht + d]);
    float t = b2f(HT[(size_t)m * ldht + nseg + d]);
    float x = b2f(X[idx]);
    X[idx] = __float2bfloat16(t * h + (1.f - t) * x);
}

// ---------------------------------------------------------------------------
// Transpose x2-half of [NT,P] into [B,P,S]
// ---------------------------------------------------------------------------
__global__ void k_transpose(const bf16* __restrict__ src, bf16* __restrict__ dst) {
    int idx = blockIdx.x * 256 + threadIdx.x;
    if (idx >= B_ * P_ * S_) return;
    int j = idx & (S_ - 1);
    int rest = idx >> 7;
    int p = rest % P_;
    int b = rest / P_;
    dst[idx] = src[((size_t)(b * S_ + j)) * P_ + p];
}

// ---------------------------------------------------------------------------
// sim[b,i,j] = dot_p(p1,p2) + sum_p 1/(1+|q1-q2|); block=b*128+i, thread=j
// ---------------------------------------------------------------------------
__global__ __launch_bounds__(128) void k_sim(const bf16* __restrict__ Pmat,
                                             const bf16* __restrict__ Qmat,
                                             const bf16* __restrict__ PT,
                                             const bf16* __restrict__ QT,
                                             float* __restrict__ SIM) {
    int bi = blockIdx.x;
    int b = bi >> 7;
    int j = threadIdx.x;
    __shared__ float p1[P_], q1[P_];
    const bf16* prow = Pmat + (size_t)bi * P_;
    const bf16* qrow = Qmat + (size_t)bi * P_;
    for (int t = j; t < P_; t += 128) { p1[t] = b2f(prow[t]); q1[t] = b2f(qrow[t]); }
    __syncthreads();
    const bf16* pt = PT + (size_t)b * P_ * S_;
    const bf16* qt = QT + (size_t)b * P_ * S_;
    float acc1 = 0.f, acc2 = 0.f;
    for (int p = 0; p < P_; ++p) {
        float v = b2f(pt[p * S_ + j]);
        float u = b2f(qt[p * S_ + j]);
        acc1 += p1[p] * v;
        acc2 += 1.f / (1.f + fabsf(q1[p] - u));
    }
    SIM[(size_t)bi * S_ + j] = acc1 + acc2;
}

// ---------------------------------------------------------------------------
// Softmax-weighted average (validated round 3/4).
// ---------------------------------------------------------------------------
template <int TRANS>
__global__ __launch_bounds__(128) void k_av(const float* __restrict__ SIM,
                                            const bf16* __restrict__ E,
                                            bf16* __restrict__ OUT) {
    int blk = blockIdx.x;
    int b = blk >> 7;
    int r = blk & (S_ - 1);
    int t = threadIdx.x;
    __shared__ float w[S_];
    __shared__ float red[S_];
    float x;
    if (TRANS == 0) x = SIM[(size_t)blk * S_ + t];
    else            x = SIM[((size_t)b * S_ + t) * S_ + r];
    red[t] = x;
    __syncthreads();
    for (int s = 64; s > 0; s >>= 1) {
        if (t < s) red[t] = fmaxf(red[t], red[t + s]);
        __syncthreads();
    }
    float mx = red[0];
    __syncthreads();
    float ex = expf(x - mx);
    red[t] = ex;
    __syncthreads();
    for (int s = 64; s > 0; s >>= 1) {
        if (t < s) red[t] += red[t + s];
        __syncthreads();
    }
    w[t] = ex / red[0];
    __syncthreads();
    const bf16* Esrc = E + (TRANS == 0 ? (size_t)NT1 * D_ : 0) + (size_t)b * S_ * D_;
    bf16* orow = OUT + (TRANS == 0 ? (size_t)blk * D_ : (size_t)(NT1 + blk) * D_);
    for (int d = t; d < D_; d += 128) {
        float acc = 0.f;
        for (int s = 0; s < S_; ++s) acc += w[s] * b2f(Esrc[(size_t)s * D_ + d]);
        orow[d] = __float2bfloat16(acc);
    }
}

// ---------------------------------------------------------------------------
// Pool: out[b] = concat(max_i v1, max_j v2, sum_i v1, sum_j v2)  [B,4P] fp32
// ---------------------------------------------------------------------------
__global__ __launch_bounds__(256) void k_pool(const bf16* __restrict__ V,
                                              float* __restrict__ OUT) {
    int b = blockIdx.x;
    int c = threadIdx.x;
    if (c >= P_) return;
    const bf16* v1 = V + (size_t)b * S_ * P_;
    const bf16* v2 = V + (size_t)(NT1 + b * S_) * P_;
    float mx1 = -INFINITY, mx2 = -INFINITY, s1 = 0.f, s2 = 0.f;
    for (int i = 0; i < S_; ++i) {
        float a = b2f(v1[(size_t)i * P_ + c]);
        mx1 = fmaxf(mx1, a); s1 += a;
        float bb = b2f(v2[(size_t)i * P_ + c]);
        mx2 = fmaxf(mx2, bb); s2 += bb;
    }
    float* o = OUT + (size_t)b * 4 * P_;
    o[c] = mx1; o[P_ + c] = mx2; o[2 * P_ + c] = s1; o[3 * P_ + c] = s2;
}

// ---------------------------------------------------------------------------
// Small fp32 SIMD GEMM for the M=32 tail
// ---------------------------------------------------------------------------
#define SBM 64
#define SBN 64
#define SBK 16
__global__ __launch_bounds__(256) void k_gemm_f32(
    const float* __restrict__ A, const float* __restrict__ W,
    const float* __restrict__ bias, float* __restrict__ C,
    int M, int N, int K, int act) {
    __shared__ float As[SBK][SBM + 1];
    __shared__ float Ws[SBK][SBN + 1];
    int tid = threadIdx.x;
    int bm = blockIdx.y * SBM;
    int bn = blockIdx.x * SBN;
    int tx = tid & 15, ty = tid >> 4;
    float acc[4][4] = {};
    for (int k0 = 0; k0 < K; k0 += SBK) {
#pragma unroll
        for (int l = 0; l < 4; ++l) {
            int idx = tid + l * 256;
            int m = idx >> 4, kk = idx & 15;
            int gm = bm + m, gk = k0 + kk;
            As[kk][m] = (gm < M && gk < K) ? A[(size_t)gm * K + gk] : 0.f;
        }
#pragma unroll
        for (int l = 0; l < 4; ++l) {
            int idx = tid + l * 256;
            int kk = idx >> 6, n = idx & 63;
            int gk = k0 + kk, gn = bn + n;
            Ws[kk][n] = (gk < K && gn < N) ? W[(size_t)gk * N + gn] : 0.f;
        }
        __syncthreads();
#pragma unroll
        for (int kk = 0; kk < SBK; ++kk) {
            float a[4], w[4];
#pragma unroll
            for (int i = 0; i < 4; ++i) a[i] = As[kk][ty * 4 + i];
#pragma unroll
            for (int j = 0; j < 4; ++j) w[j] = Ws[kk][tx * 4 + j];
#pragma unroll
            for (int i = 0; i < 4; ++i)
#pragma unroll
                for (int j = 0; j < 4; ++j) acc[i][j] += a[i] * w[j];
        }
        __syncthreads();
    }
#pragma unroll
    for (int i = 0; i < 4; ++i) {
        int gm = bm + ty * 4 + i;
        if (gm >= M) continue;
#pragma unroll
        for (int j = 0; j < 4; ++j) {
            int gn = bn + tx * 4 + j;
            if (gn >= N) continue;
            float v = acc[i][j] + bias[gn];
            if (act == 1) v = fmaxf(v, 0.f);
            else if (act == 2) v = 1.f / (1.f + expf(-v));
            C[(size_t)gm * N + gn] = v;
        }
    }
}

// Sentinel fill (diagnostic: absmax ~555 => ws_size too small)
__global__ void k_fillf(float* dst, int n, float v) {
    int i = blockIdx.x * 256 + threadIdx.x;
    if (i < n) dst[i] = v;
}

// ---------------------------------------------------------------------------
// Launch
// ---------------------------------------------------------------------------
extern "C" void kernel_launch(void* const* d_in, const int* in_sizes, int n_in,
                              void* d_out, int out_size, void* d_ws, size_t ws_size,
                              hipStream_t stream) {
    const int* x1 = (const int*)d_in[0];
    const int* x2 = (const int*)d_in[1];
    const float* emb = (const float*)d_in[2];
    const float *hw1_Wh = (const float*)d_in[3],  *hw1_bh = (const float*)d_in[4];
    const float *hw1_Wt = (const float*)d_in[5],  *hw1_bt = (const float*)d_in[6];
    const float *hw2_Wh = (const float*)d_in[7],  *hw2_bh = (const float*)d_in[8];
    const float *hw2_Wt = (const float*)d_in[9],  *hw2_bt = (const float*)d_in[10];
    const float *mul_W1 = (const float*)d_in[11], *mul_b1 = (const float*)d_in[12];
    const float *mul_W2 = (const float*)d_in[13], *mul_b2 = (const float*)d_in[14];
    const float *dist_W1 = (const float*)d_in[15], *dist_b1 = (const float*)d_in[16];
    const float *dist_W2 = (const float*)d_in[17], *dist_b2 = (const float*)d_in[18];
    const float *cmp_W1 = (const float*)d_in[19], *cmp_b1 = (const float*)d_in[20];
    const float *cmp_W2 = (const float*)d_in[21], *cmp_b2 = (const float*)d_in[22];
    const float *chw1_Wh = (const float*)d_in[23], *chw1_bh = (const float*)d_in[24];
    const float *chw1_Wt = (const float*)d_in[25], *chw1_bt = (const float*)d_in[26];
    const float *chw2_Wh = (const float*)d_in[27], *chw2_bh = (const float*)d_in[28];
    const float *chw2_Wt = (const float*)d_in[29], *chw2_bt = (const float*)d_in[30];
    const float *agg_W1 = (const float*)d_in[31], *agg_b1 = (const float*)d_in[32];
    const float *agg_W2 = (const float*)d_in[33], *agg_b2 = (const float*)d_in[34];
    const float *out_W = (const float*)d_in[35], *out_b = (const float*)d_in[36];

    // ---- Workspace layout (elems) ----
    const size_t nED = (size_t)NT * D_;        // 2,457,600
    const size_t nEP = (size_t)NT * P_;        // 1,638,400
    const size_t nCht = (size_t)NT * 600;      // 4,915,200
    const size_t nCat = (size_t)NT * 1216;     // 9,961,472
    const size_t nTR = (size_t)B_ * P_ * S_;   //   819,200
    const size_t nWT = 1286144;                // converted weights total
    size_t bf16_elems = 2 * nED + 2 * nEP + nCht + nCat + nWT;
    size_t f32_elems = (size_t)B_ * 4 * P_ + 2 * (size_t)B_ * P_;
    size_t need = bf16_elems * 2 + f32_elems * 4 + 64;
    if (ws_size < need) {
        k_fillf<<<dim3(1), dim3(256), 0, stream>>>((float*)d_out, B_ * 3, 555.f);
        return;
    }
    bf16* Eb  = (bf16*)d_ws;            // [NT,300]
    bf16* A2b = Eb + nED;               // [NT,300] ATT
    bf16* Pb  = A2b + nED;              // [NT,200] mul proj -> V
    bf16* Qb  = Pb + nEP;               // [NT,200] dist proj
    bf16* Cht = Qb + nEP;               // [NT,600] packed h|t / hidden / PT/QT/SIM
    bf16* CatB = Cht + nCht;            // [NT,1216] dense concat features
    bf16* WTp = CatB + nCat;            // converted weights pool
    float* POOL = (float*)(WTp + nWT);  // [B,4P]
    float* G1 = POOL + (size_t)B_ * 4 * P_;
    float* G2 = G1 + (size_t)B_ * P_;
    // overlays inside Cht:
    bf16* PTb = Cht;
    bf16* QTb = Cht + nTR;
    float* SIM = (float*)(Cht + 2 * nTR);   // byte offset 3,276,800: 16B-aligned

    // converted-weight sub-buffers (elems), Npad mult of 128
    bf16* WT_hw1 = WTp + 0;        // 640x320
    bf16* WT_hw2 = WTp + 204800;   // 640x320
    bf16* WT_md  = WTp + 409600;   // 512x320 (mul_W1 | dist_W1)
    bf16* WT_m2  = WTp + 573440;   // 256x224
    bf16* WT_d2  = WTp + 630784;   // 256x224
    bf16* WT_c1  = WTp + 688128;   // 256x1216
    bf16* WT_c2  = WTp + 999424;   // 256x224
    bf16* WT_ch1 = WTp + 1056768;  // 512x224 (chw1_Wh | chw1_Wt)
    bf16* WT_ch2 = WTp + 1171456;  // 512x224

    dim3 blk256(256);

    // 0. fused weight conversion (1 dispatch)
    ConvTable T;
    const float* s1[9] = {hw1_Wh, hw2_Wh, mul_W1, mul_W2, dist_W2, cmp_W1, cmp_W2, chw1_Wh, chw2_Wh};
    const float* s2[9] = {hw1_Wt, hw2_Wt, dist_W1, nullptr, nullptr, nullptr, nullptr, chw1_Wt, chw2_Wt};
    bf16* dsts[9] = {WT_hw1, WT_hw2, WT_md, WT_m2, WT_d2, WT_c1, WT_c2, WT_ch1, WT_ch2};
    int Ks[9]  = {300, 300, 300, 200, 200, 1200, 200, 200, 200};
    int N1s[9] = {300, 300, 200, 200, 200, 200, 200, 200, 200};
    int N2s[9] = {300, 300, 200, 0, 0, 0, 0, 200, 200};
    int Kps[9] = {320, 320, 320, 224, 224, 1216, 224, 224, 224};
    int Nps[9] = {640, 640, 512, 256, 256, 256, 256, 512, 512};
    unsigned long long base = 0;
    for (int i = 0; i < 9; ++i) {
        T.W1[i] = s1[i]; T.W2[i] = s2[i]; T.dst[i] = dsts[i];
        T.K[i] = Ks[i]; T.N1[i] = N1s[i]; T.N2[i] = N2s[i]; T.Kpad[i] = Kps[i];
        T.base[i] = base;
        base += (unsigned long long)Kps[i] * Nps[i];
    }
    T.total = base;   // 1,286,144
    k_convw<<<dim3((unsigned)((base + 255) / 256)), blk256, 0, stream>>>(T);

    // 1. embed
    k_embed<<<dim3((NT * D_ + 255) / 256), blk256, 0, stream>>>(x1, x2, emb, Eb);

    int hwyD = (NT * D_ + 255) / 256, hwyP = (NT * P_ + 255) / 256;

    // 2-3. embedding highway stack: combined h|t GEMM (N=600) + combine
    k_mfma_gemm<<<dim3(5, 128), blk256, 0, stream>>>(Eb, 300, WT_hw1, 320, 300,
        Cht, 600, 600, 300, hw1_bh, hw1_bt, 1, 2);
    k_highway2<<<dim3(hwyD), blk256, 0, stream>>>(Cht, 600, 300, Eb, 300);
    k_mfma_gemm<<<dim3(5, 128), blk256, 0, stream>>>(Eb, 300, WT_hw2, 320, 300,
        Cht, 600, 600, 300, hw2_bh, hw2_bt, 1, 2);
    k_highway2<<<dim3(hwyD), blk256, 0, stream>>>(Cht, 600, 300, Eb, 300);

    // 4-5. mul+dist W1 combined (N=400) -> Cht; then W2s -> Pb, Qb
    k_mfma_gemm<<<dim3(4, 128), blk256, 0, stream>>>(Eb, 300, WT_md, 320, 300,
        Cht, 400, 400, 200, mul_b1, dist_b1, 1, 1);
    k_mfma_gemm<<<dim3(2, 128), blk256, 0, stream>>>(Cht, 400, WT_m2, 224, 200,
        Pb, 200, 200, 200, mul_b2, mul_b2, 1, 1);
    k_mfma_gemm<<<dim3(2, 128), blk256, 0, stream>>>(Cht + 200, 400, WT_d2, 224, 200,
        Qb, 200, 200, 200, dist_b2, dist_b2, 1, 1);

    // 6. transpose x2-halves into Cht overlay
    int nTRb = (int)((nTR + 255) / 256);
    k_transpose<<<dim3(nTRb), blk256, 0, stream>>>(Pb + (size_t)NT1 * P_, PTb);
    k_transpose<<<dim3(nTRb), blk256, 0, stream>>>(Qb + (size_t)NT1 * P_, QTb);

    // 7. sim
    k_sim<<<dim3(NT1), dim3(128), 0, stream>>>(Pb, Qb, PTb, QTb, SIM);

    // 8. attention: beta -> A2b rows 0..4095, alpha -> rows 4096..8191
    k_av<0><<<dim3(NT1), dim3(128), 0, stream>>>(SIM, Eb, A2b);
    k_av<1><<<dim3(NT1), dim3(128), 0, stream>>>(SIM, Eb, A2b);

    // 9. compare ff: dense concat, then plain GEMMs (K=1216 incl zero pad)
    k_cat<<<dim3((NT * 304 + 255) / 256), blk256, 0, stream>>>(Eb, A2b, CatB);
    k_mfma_gemm<<<dim3(2, 128), blk256, 0, stream>>>(CatB, 1216, WT_c1, 1216, 1216,
        Cht, 200, 200, 200, cmp_b1, cmp_b1, 1, 1);
    k_mfma_gemm<<<dim3(2, 128), blk256, 0, stream>>>(Cht, 200, WT_c2, 224, 200,
        Pb, 200, 200, 200, cmp_b2, cmp_b2, 1, 1);

    // 10-11. compare highway stack (combined N=400 GEMMs)
    k_mfma_gemm<<<dim3(4, 128), blk256, 0, stream>>>(Pb, 200, WT_ch1, 224, 200,
        Cht, 400, 400, 200, chw1_bh, chw1_bt, 1, 2);
    k_highway2<<<dim3(hwyP), blk256, 0, stream>>>(Cht, 400, 200, Pb, 200);
    k_mfma_gemm<<<dim3(4, 128), blk256, 0, stream>>>(Pb, 200, WT_ch2, 224, 200,
        Cht, 400, 400, 200, chw2_bh, chw2_bt, 1, 2);
    k_highway2<<<dim3(hwyP), blk256, 0, stream>>>(Cht, 400, 200, Pb, 200);

    // 12. pool
    k_pool<<<dim3(B_), blk256, 0, stream>>>(Pb, POOL);

    // 13-15. aggregate ff + final linear (fp32 SIMD, M=32); last writes d_out
    k_gemm_f32<<<dim3(4, 1), blk256, 0, stream>>>(POOL, agg_W1, agg_b1, G1, B_, P_, 4 * P_, 1);
    k_gemm_f32<<<dim3(4, 1), blk256, 0, stream>>>(G1, agg_W2, agg_b2, G2, B_, P_, P_, 1);
    k_gemm_f32<<<dim3(1, 1), blk256, 0, stream>>>(G2, out_W, out_b, (float*)d_out, B_, 3, P_, 0);
}

// Round 6
// 489.523 us; speedup vs baseline: 2.9614x; 1.3684x over previous
//
#include <hip/hip_runtime.h>
#include <hip/hip_bf16.h>
#include <math.h>

// Problem constants
#define B_   32
#define S_   128
#define V_   30000
#define D_   300
#define P_   200
#define NT   8192         // 2*B*S token rows: x1 rows 0..4095, x2 rows 4096..8191
#define NT1  4096

typedef __hip_bfloat16 bf16;
typedef __attribute__((ext_vector_type(8))) __bf16 bf16x8;
typedef __attribute__((ext_vector_type(4))) float f32x4;

__device__ __forceinline__ float b2f(bf16 v) { return __bfloat162float(v); }
__device__ __forceinline__ short f2s(float v) { bf16 h = __float2bfloat16(v); return *(short*)&h; }
__device__ __forceinline__ float s2f(short s) { bf16 h; *(short*)&h = s; return __bfloat162float(h); }

// ---------------------------------------------------------------------------
// Fused weight conversion: fp32 [K][N] (optionally two sources concat along N)
// -> bf16 WT[Npad][Kpad], WT[n*Kpad+k] = W[k][n], zero pads (Npad mult of 128
// so B staging needs no guards anywhere).
// ---------------------------------------------------------------------------
struct ConvTable {
    const float* W1[9]; const float* W2[9]; bf16* dst[9];
    int K[9], N1[9], N2[9], Kpad[9];
    unsigned long long base[9]; unsigned long long total;
};

__global__ void k_convw(ConvTable T) {
    unsigned long long idx = (unsigned long long)blockIdx.x * 256 + threadIdx.x;
    if (idx >= T.total) return;
    int e = 0;
#pragma unroll
    for (int i = 1; i < 9; ++i) if (idx >= T.base[i]) e = i;
    unsigned long long local = idx - T.base[e];
    int Kpad = T.Kpad[e];
    int n = (int)(local / Kpad);
    int k = (int)(local - (unsigned long long)n * Kpad);
    float v = 0.f;
    if (k < T.K[e]) {
        if (n < T.N1[e]) v = T.W1[e][(size_t)k * T.N1[e] + n];
        else if (n < T.N1[e] + T.N2[e]) v = T.W2[e][(size_t)k * T.N2[e] + (n - T.N1[e])];
    }
    T.dst[e][local] = __float2bfloat16(v);
}

// ---------------------------------------------------------------------------
// fp32 transposes for the skinny tail: T[n*K+k] = W[k*N+n]
// agg_W1 [800,200] -> T1 [200][800]; agg_W2 [200,200] -> T2 [200][200];
// out_W [200,3] -> T3 [3][200]. One dispatch.
// ---------------------------------------------------------------------------
__global__ void k_convt(const float* __restrict__ W1, const float* __restrict__ W2,
                        const float* __restrict__ W3, float* __restrict__ T1,
                        float* __restrict__ T2, float* __restrict__ T3) {
    int idx = blockIdx.x * 256 + threadIdx.x;
    if (idx < 160000) {                         // 200 x 800
        int n = idx / 800, k = idx - n * 800;
        T1[idx] = W1[k * 200 + n];
    } else if (idx < 200000) {                  // 200 x 200
        int l = idx - 160000;
        int n = l / 200, k = l - n * 200;
        T2[l] = W2[k * 200 + n];
    } else if (idx < 200600) {                  // 3 x 200
        int l = idx - 200000;
        int n = l / 200, k = l - n * 200;
        T3[l] = W3[k * 3 + n];
    }
}

// ---------------------------------------------------------------------------
// Skinny GEMM for tiny M: one wave per output element.
// C[m,n] = act(dot(A[m,:], WT[n,:]) + bias[n]); K mult of 4.
// Wave's 64 lanes stride the K/4 float4 chunks, then shuffle-reduce.
// ---------------------------------------------------------------------------
__global__ __launch_bounds__(256) void k_skinny(
    const float* __restrict__ A, const float* __restrict__ WT,
    const float* __restrict__ bias, float* __restrict__ C,
    int M, int N, int K, int act) {
    int wave = (blockIdx.x * 256 + threadIdx.x) >> 6;
    int lane = threadIdx.x & 63;
    if (wave >= M * N) return;
    int m = wave / N, n = wave - m * N;
    const float4* a4 = (const float4*)(A + (size_t)m * K);
    const float4* w4 = (const float4*)(WT + (size_t)n * K);
    int K4 = K >> 2;
    float acc = 0.f;
    for (int i = lane; i < K4; i += 64) {
        float4 av = a4[i], wv = w4[i];
        acc += av.x * wv.x + av.y * wv.y + av.z * wv.z + av.w * wv.w;
    }
#pragma unroll
    for (int off = 32; off > 0; off >>= 1) acc += __shfl_down(acc, off, 64);
    if (lane == 0) {
        float v = acc + bias[n];
        if (act == 1) v = fmaxf(v, 0.f);
        C[(size_t)m * N + n] = v;
    }
}

// ---------------------------------------------------------------------------
// Embedding gather: fp32 emb -> bf16 E
// ---------------------------------------------------------------------------
__global__ void k_embed(const int* __restrict__ x1, const int* __restrict__ x2,
                        const float* __restrict__ emb, bf16* __restrict__ E) {
    int idx = blockIdx.x * 256 + threadIdx.x;
    if (idx >= NT * D_) return;
    int r = idx / D_;
    int d = idx - r * D_;
    int tok = (r < NT1) ? x1[r] : x2[r - NT1];
    if ((unsigned)tok >= (unsigned)V_) tok = 0;
    E[idx] = __float2bfloat16(emb[(size_t)tok * D_ + d]);
}

// ---------------------------------------------------------------------------
// Dense concat features: CatB[m, 0:1216] = [E, ATT, E-ATT, E*ATT, 0-pad]
// ---------------------------------------------------------------------------
__global__ void k_cat(const bf16* __restrict__ E, const bf16* __restrict__ ATT,
                      bf16* __restrict__ CatB) {
    int idx = blockIdx.x * 256 + threadIdx.x;   // 4-elem chunk id
    const int total = NT * 304;                 // 1216/4 chunks per row
    if (idx >= total) return;
    int m = idx / 304;
    int c = idx - m * 304;
    short4 out = {0, 0, 0, 0};
    if (c < 300) {
        int sel = c / 75;
        int kc = (c - sel * 75) * 4;
        short4 ev = *(const short4*)((const short*)E + (size_t)m * D_ + kc);
        short4 av = *(const short4*)((const short*)ATT + (size_t)m * D_ + kc);
        const short* ep = (const short*)&ev;
        const short* ap = (const short*)&av;
        short* op = (short*)&out;
#pragma unroll
        for (int i = 0; i < 4; ++i) {
            float e = s2f(ep[i]), a = s2f(ap[i]);
            float v = (sel == 0) ? e : (sel == 1) ? a : (sel == 2) ? (e - a) : (e * a);
            op[i] = f2s(v);
        }
    }
    *(short4*)((short*)CatB + (size_t)m * 1216 + c * 4) = out;
}

// ---------------------------------------------------------------------------
// MFMA GEMM (validated round 5): block tile 64(M) x 128(N), 4 waves 2x2,
// each 32x64 via 16x16x32 MFMA. WT pre-transposed/padded.
// ---------------------------------------------------------------------------
#define TM 64
#define TN 128
#define TK 32
#define TKP 40

__global__ __launch_bounds__(256) void k_mfma_gemm(
    const bf16* __restrict__ A, int lda,
    const bf16* __restrict__ WT, int Kpad, int K,
    bf16* __restrict__ C, int ldc, int Ntot, int N1,
    const float* __restrict__ bias1, const float* __restrict__ bias2,
    int act1, int act2)
{
    __shared__ short As[TM][TKP];
    __shared__ short Bs[TN][TKP];
    int tid = threadIdx.x;
    int w = tid >> 6, lane = tid & 63, quad = lane >> 4, l16 = lane & 15;
    int bm = blockIdx.y * TM;
    int bn = blockIdx.x * TN;
    int wr = (w & 1) * 32;
    int wc = (w >> 1) * 64;

    int ar = tid >> 2;            // 0..63 : A row in tile
    int ac = (tid & 3) * 8;       // 0/8/16/24
    int br = tid >> 1;            // 0..127 : B n-row
    int bc = (tid & 1) * 16;      // 0/16
    const short* Ash = (const short*)A;
    const short* Wsh = (const short*)WT;

    f32x4 acc[2][4];
#pragma unroll
    for (int i = 0; i < 2; ++i)
#pragma unroll
        for (int j = 0; j < 4; ++j)
#pragma unroll
            for (int r = 0; r < 4; ++r) acc[i][j][r] = 0.f;

    for (int k0 = 0; k0 < Kpad; k0 += TK) {
        {
            int k = k0 + ac;
            const short* src = Ash + (size_t)(bm + ar) * lda + k;
            if (k + 8 <= K) {
                short4 v0 = ((const short4*)src)[0];
                short4 v1 = ((const short4*)src)[1];
                *(short4*)&As[ar][ac] = v0;
                *(short4*)&As[ar][ac + 4] = v1;
            } else {
#pragma unroll
                for (int i = 0; i < 8; ++i)
                    As[ar][ac + i] = (k + i < K) ? src[i] : (short)0;
            }
        }
        {
            const short* src = Wsh + (size_t)(bn + br) * Kpad + k0 + bc;
            short4 v0 = ((const short4*)src)[0];
            short4 v1 = ((const short4*)src)[1];
            short4 v2 = ((const short4*)src)[2];
            short4 v3 = ((const short4*)src)[3];
            short4* q = (short4*)&Bs[br][bc];
            q[0] = v0; q[1] = v1; q[2] = v2; q[3] = v3;
        }
        __syncthreads();
        {
            bf16x8 a[2], b[4];
#pragma unroll
            for (int mt = 0; mt < 2; ++mt)
                a[mt] = *(const bf16x8*)&As[wr + mt * 16 + l16][quad * 8];
#pragma unroll
            for (int nt = 0; nt < 4; ++nt)
                b[nt] = *(const bf16x8*)&Bs[wc + nt * 16 + l16][quad * 8];
#pragma unroll
            for (int mt = 0; mt < 2; ++mt)
#pragma unroll
                for (int nt = 0; nt < 4; ++nt)
                    acc[mt][nt] = __builtin_amdgcn_mfma_f32_16x16x32_bf16(a[mt], b[nt], acc[mt][nt], 0, 0, 0);
        }
        __syncthreads();
    }
#pragma unroll
    for (int mt = 0; mt < 2; ++mt) {
        int row = bm + wr + mt * 16 + quad * 4;
#pragma unroll
        for (int nt = 0; nt < 4; ++nt) {
            int col = bn + wc + nt * 16 + l16;
            if (col >= Ntot) continue;
            float bv; int act;
            if (col < N1) { bv = bias1[col]; act = act1; }
            else          { bv = bias2[col - N1]; act = act2; }
#pragma unroll
            for (int r = 0; r < 4; ++r) {
                float v = acc[mt][nt][r] + bv;
                if (act == 1) v = fmaxf(v, 0.f);
                else if (act == 2) v = 1.f / (1.f + expf(-v));
                C[(size_t)(row + r) * ldc + col] = __float2bfloat16(v);
            }
        }
    }
}

// ---------------------------------------------------------------------------
// Highway combine from packed h|t buffer: X = t*h + (1-t)*X
// ---------------------------------------------------------------------------
__global__ void k_highway2(const bf16* __restrict__ HT, int ldht, int nseg,
                           bf16* __restrict__ X, int width) {
    int idx = blockIdx.x * 256 + threadIdx.x;
    if (idx >= NT * width) return;
    int m = idx / width, d = idx - m * width;
    float h = b2f(HT[(size_t)m * ldht + d]);
    float t = b2f(HT[(size_t)m * ldht + nseg + d]);
    float x = b2f(X[idx]);
    X[idx] = __float2bfloat16(t * h + (1.f - t) * x);
}

// ---------------------------------------------------------------------------
// Transpose x2-half of [NT,P] into [B,P,S]
// ---------------------------------------------------------------------------
__global__ void k_transpose(const bf16* __restrict__ src, bf16* __restrict__ dst) {
    int idx = blockIdx.x * 256 + threadIdx.x;
    if (idx >= B_ * P_ * S_) return;
    int j = idx & (S_ - 1);
    int rest = idx >> 7;
    int p = rest % P_;
    int b = rest / P_;
    dst[idx] = src[((size_t)(b * S_ + j)) * P_ + p];
}

// ---------------------------------------------------------------------------
// sim[b,i,j] = dot_p(p1,p2) + sum_p 1/(1+|q1-q2|); block=b*128+i, thread=j
// ---------------------------------------------------------------------------
__global__ __launch_bounds__(128) void k_sim(const bf16* __restrict__ Pmat,
                                             const bf16* __restrict__ Qmat,
                                             const bf16* __restrict__ PT,
                                             const bf16* __restrict__ QT,
                                             float* __restrict__ SIM) {
    int bi = blockIdx.x;
    int b = bi >> 7;
    int j = threadIdx.x;
    __shared__ float p1[P_], q1[P_];
    const bf16* prow = Pmat + (size_t)bi * P_;
    const bf16* qrow = Qmat + (size_t)bi * P_;
    for (int t = j; t < P_; t += 128) { p1[t] = b2f(prow[t]); q1[t] = b2f(qrow[t]); }
    __syncthreads();
    const bf16* pt = PT + (size_t)b * P_ * S_;
    const bf16* qt = QT + (size_t)b * P_ * S_;
    float acc1 = 0.f, acc2 = 0.f;
    for (int p = 0; p < P_; ++p) {
        float v = b2f(pt[p * S_ + j]);
        float u = b2f(qt[p * S_ + j]);
        acc1 += p1[p] * v;
        acc2 += 1.f / (1.f + fabsf(q1[p] - u));
    }
    SIM[(size_t)bi * S_ + j] = acc1 + acc2;
}

// ---------------------------------------------------------------------------
// Softmax-weighted average (validated round 3/4/5).
// ---------------------------------------------------------------------------
template <int TRANS>
__global__ __launch_bounds__(128) void k_av(const float* __restrict__ SIM,
                                            const bf16* __restrict__ E,
                                            bf16* __restrict__ OUT) {
    int blk = blockIdx.x;
    int b = blk >> 7;
    int r = blk & (S_ - 1);
    int t = threadIdx.x;
    __shared__ float w[S_];
    __shared__ float red[S_];
    float x;
    if (TRANS == 0) x = SIM[(size_t)blk * S_ + t];
    else            x = SIM[((size_t)b * S_ + t) * S_ + r];
    red[t] = x;
    __syncthreads();
    for (int s = 64; s > 0; s >>= 1) {
        if (t < s) red[t] = fmaxf(red[t], red[t + s]);
        __syncthreads();
    }
    float mx = red[0];
    __syncthreads();
    float ex = expf(x - mx);
    red[t] = ex;
    __syncthreads();
    for (int s = 64; s > 0; s >>= 1) {
        if (t < s) red[t] += red[t + s];
        __syncthreads();
    }
    w[t] = ex / red[0];
    __syncthreads();
    const bf16* Esrc = E + (TRANS == 0 ? (size_t)NT1 * D_ : 0) + (size_t)b * S_ * D_;
    bf16* orow = OUT + (TRANS == 0 ? (size_t)blk * D_ : (size_t)(NT1 + blk) * D_);
    for (int d = t; d < D_; d += 128) {
        float acc = 0.f;
        for (int s = 0; s < S_; ++s) acc += w[s] * b2f(Esrc[(size_t)s * D_ + d]);
        orow[d] = __float2bfloat16(acc);
    }
}

// ---------------------------------------------------------------------------
// Pool: out[b] = concat(max_i v1, max_j v2, sum_i v1, sum_j v2)  [B,4P] fp32
// ---------------------------------------------------------------------------
__global__ __launch_bounds__(256) void k_pool(const bf16* __restrict__ V,
                                              float* __restrict__ OUT) {
    int b = blockIdx.x;
    int c = threadIdx.x;
    if (c >= P_) return;
    const bf16* v1 = V + (size_t)b * S_ * P_;
    const bf16* v2 = V + (size_t)(NT1 + b * S_) * P_;
    float mx1 = -INFINITY, mx2 = -INFINITY, s1 = 0.f, s2 = 0.f;
    for (int i = 0; i < S_; ++i) {
        float a = b2f(v1[(size_t)i * P_ + c]);
        mx1 = fmaxf(mx1, a); s1 += a;
        float bb = b2f(v2[(size_t)i * P_ + c]);
        mx2 = fmaxf(mx2, bb); s2 += bb;
    }
    float* o = OUT + (size_t)b * 4 * P_;
    o[c] = mx1; o[P_ + c] = mx2; o[2 * P_ + c] = s1; o[3 * P_ + c] = s2;
}

// Sentinel fill (diagnostic: absmax ~555 => ws_size too small)
__global__ void k_fillf(float* dst, int n, float v) {
    int i = blockIdx.x * 256 + threadIdx.x;
    if (i < n) dst[i] = v;
}

// ---------------------------------------------------------------------------
// Launch
// ---------------------------------------------------------------------------
extern "C" void kernel_launch(void* const* d_in, const int* in_sizes, int n_in,
                              void* d_out, int out_size, void* d_ws, size_t ws_size,
                              hipStream_t stream) {
    const int* x1 = (const int*)d_in[0];
    const int* x2 = (const int*)d_in[1];
    const float* emb = (const float*)d_in[2];
    const float *hw1_Wh = (const float*)d_in[3],  *hw1_bh = (const float*)d_in[4];
    const float *hw1_Wt = (const float*)d_in[5],  *hw1_bt = (const float*)d_in[6];
    const float *hw2_Wh = (const float*)d_in[7],  *hw2_bh = (const float*)d_in[8];
    const float *hw2_Wt = (const float*)d_in[9],  *hw2_bt = (const float*)d_in[10];
    const float *mul_W1 = (const float*)d_in[11], *mul_b1 = (const float*)d_in[12];
    const float *mul_W2 = (const float*)d_in[13], *mul_b2 = (const float*)d_in[14];
    const float *dist_W1 = (const float*)d_in[15], *dist_b1 = (const float*)d_in[16];
    const float *dist_W2 = (const float*)d_in[17], *dist_b2 = (const float*)d_in[18];
    const float *cmp_W1 = (const float*)d_in[19], *cmp_b1 = (const float*)d_in[20];
    const float *cmp_W2 = (const float*)d_in[21], *cmp_b2 = (const float*)d_in[22];
    const float *chw1_Wh = (const float*)d_in[23], *chw1_bh = (const float*)d_in[24];
    const float *chw1_Wt = (const float*)d_in[25], *chw1_bt = (const float*)d_in[26];
    const float *chw2_Wh = (const float*)d_in[27], *chw2_bh = (const float*)d_in[28];
    const float *chw2_Wt = (const float*)d_in[29], *chw2_bt = (const float*)d_in[30];
    const float *agg_W1 = (const float*)d_in[31], *agg_b1 = (const float*)d_in[32];
    const float *agg_W2 = (const float*)d_in[33], *agg_b2 = (const float*)d_in[34];
    const float *out_W = (const float*)d_in[35], *out_b = (const float*)d_in[36];

    // ---- Workspace layout (elems) ----
    const size_t nED = (size_t)NT * D_;        // 2,457,600
    const size_t nEP = (size_t)NT * P_;        // 1,638,400
    const size_t nCht = (size_t)NT * 600;      // 4,915,200
    const size_t nCat = (size_t)NT * 1216;     // 9,961,472
    const size_t nTR = (size_t)B_ * P_ * S_;   //   819,200
    const size_t nWT = 1286144;                // converted bf16 weights total
    const size_t nWTf = 200600;                // fp32 transposed tail weights
    size_t bf16_elems = 2 * nED + 2 * nEP + nCht + nCat + nWT;
    size_t f32_elems = (size_t)B_ * 4 * P_ + 2 * (size_t)B_ * P_ + nWTf;
    size_t need = bf16_elems * 2 + f32_elems * 4 + 64;
    if (ws_size < need) {
        k_fillf<<<dim3(1), dim3(256), 0, stream>>>((float*)d_out, B_ * 3, 555.f);
        return;
    }
    bf16* Eb  = (bf16*)d_ws;            // [NT,300]
    bf16* A2b = Eb + nED;               // [NT,300] ATT
    bf16* Pb  = A2b + nED;              // [NT,200] mul proj -> V
    bf16* Qb  = Pb + nEP;               // [NT,200] dist proj
    bf16* Cht = Qb + nEP;               // [NT,600] packed h|t / hidden / PT/QT/SIM
    bf16* CatB = Cht + nCht;            // [NT,1216] dense concat features
    bf16* WTp = CatB + nCat;            // converted bf16 weights pool
    float* POOL = (float*)(WTp + nWT);  // [B,4P]  (16B-aligned: bf16 region is 48,709,632 B)
    float* G1 = POOL + (size_t)B_ * 4 * P_;
    float* G2 = G1 + (size_t)B_ * P_;
    float* WT_a1 = G2 + (size_t)B_ * P_;  // [200][800] fp32
    float* WT_a2 = WT_a1 + 160000;        // [200][200] fp32
    float* WT_o  = WT_a2 + 40000;         // [3][200] fp32
    // overlays inside Cht:
    bf16* PTb = Cht;
    bf16* QTb = Cht + nTR;
    float* SIM = (float*)(Cht + 2 * nTR);

    // converted-weight sub-buffers (elems), Npad mult of 128
    bf16* WT_hw1 = WTp + 0;        // 640x320
    bf16* WT_hw2 = WTp + 204800;   // 640x320
    bf16* WT_md  = WTp + 409600;   // 512x320 (mul_W1 | dist_W1)
    bf16* WT_m2  = WTp + 573440;   // 256x224
    bf16* WT_d2  = WTp + 630784;   // 256x224
    bf16* WT_c1  = WTp + 688128;   // 256x1216
    bf16* WT_c2  = WTp + 999424;   // 256x224
    bf16* WT_ch1 = WTp + 1056768;  // 512x224 (chw1_Wh | chw1_Wt)
    bf16* WT_ch2 = WTp + 1171456;  // 512x224

    dim3 blk256(256);

    // 0. weight conversions
    ConvTable T;
    const float* s1[9] = {hw1_Wh, hw2_Wh, mul_W1, mul_W2, dist_W2, cmp_W1, cmp_W2, chw1_Wh, chw2_Wh};
    const float* s2[9] = {hw1_Wt, hw2_Wt, dist_W1, nullptr, nullptr, nullptr, nullptr, chw1_Wt, chw2_Wt};
    bf16* dsts[9] = {WT_hw1, WT_hw2, WT_md, WT_m2, WT_d2, WT_c1, WT_c2, WT_ch1, WT_ch2};
    int Ks[9]  = {300, 300, 300, 200, 200, 1200, 200, 200, 200};
    int N1s[9] = {300, 300, 200, 200, 200, 200, 200, 200, 200};
    int N2s[9] = {300, 300, 200, 0, 0, 0, 0, 200, 200};
    int Kps[9] = {320, 320, 320, 224, 224, 1216, 224, 224, 224};
    int Nps[9] = {640, 640, 512, 256, 256, 256, 256, 512, 512};
    unsigned long long base = 0;
    for (int i = 0; i < 9; ++i) {
        T.W1[i] = s1[i]; T.W2[i] = s2[i]; T.dst[i] = dsts[i];
        T.K[i] = Ks[i]; T.N1[i] = N1s[i]; T.N2[i] = N2s[i]; T.Kpad[i] = Kps[i];
        T.base[i] = base;
        base += (unsigned long long)Kps[i] * Nps[i];
    }
    T.total = base;   // 1,286,144
    k_convw<<<dim3((unsigned)((base + 255) / 256)), blk256, 0, stream>>>(T);
    k_convt<<<dim3((200600 + 255) / 256), blk256, 0, stream>>>(agg_W1, agg_W2, out_W,
                                                               WT_a1, WT_a2, WT_o);

    // 1. embed
    k_embed<<<dim3((NT * D_ + 255) / 256), blk256, 0, stream>>>(x1, x2, emb, Eb);

    int hwyD = (NT * D_ + 255) / 256, hwyP = (NT * P_ + 255) / 256;

    // 2-3. embedding highway stack: combined h|t GEMM (N=600) + combine
    k_mfma_gemm<<<dim3(5, 128), blk256, 0, stream>>>(Eb, 300, WT_hw1, 320, 300,
        Cht, 600, 600, 300, hw1_bh, hw1_bt, 1, 2);
    k_highway2<<<dim3(hwyD), blk256, 0, stream>>>(Cht, 600, 300, Eb, 300);
    k_mfma_gemm<<<dim3(5, 128), blk256, 0, stream>>>(Eb, 300, WT_hw2, 320, 300,
        Cht, 600, 600, 300, hw2_bh, hw2_bt, 1, 2);
    k_highway2<<<dim3(hwyD), blk256, 0, stream>>>(Cht, 600, 300, Eb, 300);

    // 4-5. mul+dist W1 combined (N=400) -> Cht; then W2s -> Pb, Qb
    k_mfma_gemm<<<dim3(4, 128), blk256, 0, stream>>>(Eb, 300, WT_md, 320, 300,
        Cht, 400, 400, 200, mul_b1, dist_b1, 1, 1);
    k_mfma_gemm<<<dim3(2, 128), blk256, 0, stream>>>(Cht, 400, WT_m2, 224, 200,
        Pb, 200, 200, 200, mul_b2, mul_b2, 1, 1);
    k_mfma_gemm<<<dim3(2, 128), blk256, 0, stream>>>(Cht + 200, 400, WT_d2, 224, 200,
        Qb, 200, 200, 200, dist_b2, dist_b2, 1, 1);

    // 6. transpose x2-halves into Cht overlay
    int nTRb = (int)((nTR + 255) / 256);
    k_transpose<<<dim3(nTRb), blk256, 0, stream>>>(Pb + (size_t)NT1 * P_, PTb);
    k_transpose<<<dim3(nTRb), blk256, 0, stream>>>(Qb + (size_t)NT1 * P_, QTb);

    // 7. sim
    k_sim<<<dim3(NT1), dim3(128), 0, stream>>>(Pb, Qb, PTb, QTb, SIM);

    // 8. attention: beta -> A2b rows 0..4095, alpha -> rows 4096..8191
    k_av<0><<<dim3(NT1), dim3(128), 0, stream>>>(SIM, Eb, A2b);
    k_av<1><<<dim3(NT1), dim3(128), 0, stream>>>(SIM, Eb, A2b);

    // 9. compare ff: dense concat, then plain GEMMs (K=1216 incl zero pad)
    k_cat<<<dim3((NT * 304 + 255) / 256), blk256, 0, stream>>>(Eb, A2b, CatB);
    k_mfma_gemm<<<dim3(2, 128), blk256, 0, stream>>>(CatB, 1216, WT_c1, 1216, 1216,
        Cht, 200, 200, 200, cmp_b1, cmp_b1, 1, 1);
    k_mfma_gemm<<<dim3(2, 128), blk256, 0, stream>>>(Cht, 200, WT_c2, 224, 200,
        Pb, 200, 200, 200, cmp_b2, cmp_b2, 1, 1);

    // 10-11. compare highway stack (combined N=400 GEMMs)
    k_mfma_gemm<<<dim3(4, 128), blk256, 0, stream>>>(Pb, 200, WT_ch1, 224, 200,
        Cht, 400, 400, 200, chw1_bh, chw1_bt, 1, 2);
    k_highway2<<<dim3(hwyP), blk256, 0, stream>>>(Cht, 400, 200, Pb, 200);
    k_mfma_gemm<<<dim3(4, 128), blk256, 0, stream>>>(Pb, 200, WT_ch2, 224, 200,
        Cht, 400, 400, 200, chw2_bh, chw2_bt, 1, 2);
    k_highway2<<<dim3(hwyP), blk256, 0, stream>>>(Cht, 400, 200, Pb, 200);

    // 12. pool
    k_pool<<<dim3(B_), blk256, 0, stream>>>(Pb, POOL);

    // 13-15. aggregate ff + final linear: wave-per-output skinny GEMMs
    k_skinny<<<dim3(1600), blk256, 0, stream>>>(POOL, WT_a1, agg_b1, G1, B_, P_, 800, 1);
    k_skinny<<<dim3(1600), blk256, 0, stream>>>(G1, WT_a2, agg_b2, G2, B_, P_, 200, 1);
    k_skinny<<<dim3(24), blk256, 0, stream>>>(G2, WT_o, out_b, (float*)d_out, B_, 3, 200, 0);
}

// Round 7
// 443.700 us; speedup vs baseline: 3.2672x; 1.1033x over previous
//
#include <hip/hip_runtime.h>
#include <hip/hip_bf16.h>
#include <math.h>

// Problem constants
#define B_   32
#define S_   128
#define V_   30000
#define D_   300
#define P_   200
#define NT   8192         // 2*B*S token rows: x1 rows 0..4095, x2 rows 4096..8191
#define NT1  4096

typedef __hip_bfloat16 bf16;
typedef __attribute__((ext_vector_type(8))) __bf16 bf16x8;
typedef __attribute__((ext_vector_type(4))) float f32x4;

__device__ __forceinline__ float b2f(bf16 v) { return __bfloat162float(v); }
__device__ __forceinline__ short f2s(float v) { bf16 h = __float2bfloat16(v); return *(short*)&h; }
__device__ __forceinline__ float s2f(short s) { bf16 h; *(short*)&h = s; return __bfloat162float(h); }

// ---------------------------------------------------------------------------
// Fused weight conversion: fp32 [K][N] (optionally two sources concat along N)
// -> bf16 WT[Npad][Kpad], WT[n*Kpad+k] = W[k][n], zero pads (Npad mult of 128
// so B staging needs no guards anywhere).
// ---------------------------------------------------------------------------
struct ConvTable {
    const float* W1[9]; const float* W2[9]; bf16* dst[9];
    int K[9], N1[9], N2[9], Kpad[9];
    unsigned long long base[9]; unsigned long long total;
};

__global__ void k_convw(ConvTable T) {
    unsigned long long idx = (unsigned long long)blockIdx.x * 256 + threadIdx.x;
    if (idx >= T.total) return;
    int e = 0;
#pragma unroll
    for (int i = 1; i < 9; ++i) if (idx >= T.base[i]) e = i;
    unsigned long long local = idx - T.base[e];
    int Kpad = T.Kpad[e];
    int n = (int)(local / Kpad);
    int k = (int)(local - (unsigned long long)n * Kpad);
    float v = 0.f;
    if (k < T.K[e]) {
        if (n < T.N1[e]) v = T.W1[e][(size_t)k * T.N1[e] + n];
        else if (n < T.N1[e] + T.N2[e]) v = T.W2[e][(size_t)k * T.N2[e] + (n - T.N1[e])];
    }
    T.dst[e][local] = __float2bfloat16(v);
}

// ---------------------------------------------------------------------------
// fp32 transposes for the skinny tail (one dispatch)
// ---------------------------------------------------------------------------
__global__ void k_convt(const float* __restrict__ W1, const float* __restrict__ W2,
                        const float* __restrict__ W3, float* __restrict__ T1,
                        float* __restrict__ T2, float* __restrict__ T3) {
    int idx = blockIdx.x * 256 + threadIdx.x;
    if (idx < 160000) {                         // 200 x 800
        int n = idx / 800, k = idx - n * 800;
        T1[idx] = W1[k * 200 + n];
    } else if (idx < 200000) {                  // 200 x 200
        int l = idx - 160000;
        int n = l / 200, k = l - n * 200;
        T2[l] = W2[k * 200 + n];
    } else if (idx < 200600) {                  // 3 x 200
        int l = idx - 200000;
        int n = l / 200, k = l - n * 200;
        T3[l] = W3[k * 3 + n];
    }
}

// ---------------------------------------------------------------------------
// Skinny GEMM for tiny M: one wave per output element (validated round 6).
// ---------------------------------------------------------------------------
__global__ __launch_bounds__(256) void k_skinny(
    const float* __restrict__ A, const float* __restrict__ WT,
    const float* __restrict__ bias, float* __restrict__ C,
    int M, int N, int K, int act) {
    int wave = (blockIdx.x * 256 + threadIdx.x) >> 6;
    int lane = threadIdx.x & 63;
    if (wave >= M * N) return;
    int m = wave / N, n = wave - m * N;
    const float4* a4 = (const float4*)(A + (size_t)m * K);
    const float4* w4 = (const float4*)(WT + (size_t)n * K);
    int K4 = K >> 2;
    float acc = 0.f;
    for (int i = lane; i < K4; i += 64) {
        float4 av = a4[i], wv = w4[i];
        acc += av.x * wv.x + av.y * wv.y + av.z * wv.z + av.w * wv.w;
    }
#pragma unroll
    for (int off = 32; off > 0; off >>= 1) acc += __shfl_down(acc, off, 64);
    if (lane == 0) {
        float v = acc + bias[n];
        if (act == 1) v = fmaxf(v, 0.f);
        C[(size_t)m * N + n] = v;
    }
}

// ---------------------------------------------------------------------------
// Embedding gather: fp32 emb -> bf16 E
// ---------------------------------------------------------------------------
__global__ void k_embed(const int* __restrict__ x1, const int* __restrict__ x2,
                        const float* __restrict__ emb, bf16* __restrict__ E) {
    int idx = blockIdx.x * 256 + threadIdx.x;
    if (idx >= NT * D_) return;
    int r = idx / D_;
    int d = idx - r * D_;
    int tok = (r < NT1) ? x1[r] : x2[r - NT1];
    if ((unsigned)tok >= (unsigned)V_) tok = 0;
    E[idx] = __float2bfloat16(emb[(size_t)tok * D_ + d]);
}

// ---------------------------------------------------------------------------
// Dense concat features: CatB[m, 0:1216] = [E, ATT, E-ATT, E*ATT, 0-pad]
// ---------------------------------------------------------------------------
__global__ void k_cat(const bf16* __restrict__ E, const bf16* __restrict__ ATT,
                      bf16* __restrict__ CatB) {
    int idx = blockIdx.x * 256 + threadIdx.x;   // 4-elem chunk id
    const int total = NT * 304;
    if (idx >= total) return;
    int m = idx / 304;
    int c = idx - m * 304;
    short4 out = {0, 0, 0, 0};
    if (c < 300) {
        int sel = c / 75;
        int kc = (c - sel * 75) * 4;
        short4 ev = *(const short4*)((const short*)E + (size_t)m * D_ + kc);
        short4 av = *(const short4*)((const short*)ATT + (size_t)m * D_ + kc);
        const short* ep = (const short*)&ev;
        const short* ap = (const short*)&av;
        short* op = (short*)&out;
#pragma unroll
        for (int i = 0; i < 4; ++i) {
            float e = s2f(ep[i]), a = s2f(ap[i]);
            float v = (sel == 0) ? e : (sel == 1) ? a : (sel == 2) ? (e - a) : (e * a);
            op[i] = f2s(v);
        }
    }
    *(short4*)((short*)CatB + (size_t)m * 1216 + c * 4) = out;
}

// ---------------------------------------------------------------------------
// MFMA GEMM (validated round 5/6): block tile 64(M) x 128(N), 4 waves 2x2,
// each 32x64 via 16x16x32 MFMA. WT pre-transposed/padded.
// ---------------------------------------------------------------------------
#define TM 64
#define TN 128
#define TK 32
#define TKP 40

__global__ __launch_bounds__(256) void k_mfma_gemm(
    const bf16* __restrict__ A, int lda,
    const bf16* __restrict__ WT, int Kpad, int K,
    bf16* __restrict__ C, int ldc, int Ntot, int N1,
    const float* __restrict__ bias1, const float* __restrict__ bias2,
    int act1, int act2)
{
    __shared__ short As[TM][TKP];
    __shared__ short Bs[TN][TKP];
    int tid = threadIdx.x;
    int w = tid >> 6, lane = tid & 63, quad = lane >> 4, l16 = lane & 15;
    int bm = blockIdx.y * TM;
    int bn = blockIdx.x * TN;
    int wr = (w & 1) * 32;
    int wc = (w >> 1) * 64;

    int ar = tid >> 2;
    int ac = (tid & 3) * 8;
    int br = tid >> 1;
    int bc = (tid & 1) * 16;
    const short* Ash = (const short*)A;
    const short* Wsh = (const short*)WT;

    f32x4 acc[2][4];
#pragma unroll
    for (int i = 0; i < 2; ++i)
#pragma unroll
        for (int j = 0; j < 4; ++j)
#pragma unroll
            for (int r = 0; r < 4; ++r) acc[i][j][r] = 0.f;

    for (int k0 = 0; k0 < Kpad; k0 += TK) {
        {
            int k = k0 + ac;
            const short* src = Ash + (size_t)(bm + ar) * lda + k;
            if (k + 8 <= K) {
                short4 v0 = ((const short4*)src)[0];
                short4 v1 = ((const short4*)src)[1];
                *(short4*)&As[ar][ac] = v0;
                *(short4*)&As[ar][ac + 4] = v1;
            } else {
#pragma unroll
                for (int i = 0; i < 8; ++i)
                    As[ar][ac + i] = (k + i < K) ? src[i] : (short)0;
            }
        }
        {
            const short* src = Wsh + (size_t)(bn + br) * Kpad + k0 + bc;
            short4 v0 = ((const short4*)src)[0];
            short4 v1 = ((const short4*)src)[1];
            short4 v2 = ((const short4*)src)[2];
            short4 v3 = ((const short4*)src)[3];
            short4* q = (short4*)&Bs[br][bc];
            q[0] = v0; q[1] = v1; q[2] = v2; q[3] = v3;
        }
        __syncthreads();
        {
            bf16x8 a[2], b[4];
#pragma unroll
            for (int mt = 0; mt < 2; ++mt)
                a[mt] = *(const bf16x8*)&As[wr + mt * 16 + l16][quad * 8];
#pragma unroll
            for (int nt = 0; nt < 4; ++nt)
                b[nt] = *(const bf16x8*)&Bs[wc + nt * 16 + l16][quad * 8];
#pragma unroll
            for (int mt = 0; mt < 2; ++mt)
#pragma unroll
                for (int nt = 0; nt < 4; ++nt)
                    acc[mt][nt] = __builtin_amdgcn_mfma_f32_16x16x32_bf16(a[mt], b[nt], acc[mt][nt], 0, 0, 0);
        }
        __syncthreads();
    }
#pragma unroll
    for (int mt = 0; mt < 2; ++mt) {
        int row = bm + wr + mt * 16 + quad * 4;
#pragma unroll
        for (int nt = 0; nt < 4; ++nt) {
            int col = bn + wc + nt * 16 + l16;
            if (col >= Ntot) continue;
            float bv; int act;
            if (col < N1) { bv = bias1[col]; act = act1; }
            else          { bv = bias2[col - N1]; act = act2; }
#pragma unroll
            for (int r = 0; r < 4; ++r) {
                float v = acc[mt][nt][r] + bv;
                if (act == 1) v = fmaxf(v, 0.f);
                else if (act == 2) v = 1.f / (1.f + expf(-v));
                C[(size_t)(row + r) * ldc + col] = __float2bfloat16(v);
            }
        }
    }
}

// ---------------------------------------------------------------------------
// Highway combine from packed h|t buffer: X = t*h + (1-t)*X
// ---------------------------------------------------------------------------
__global__ void k_highway2(const bf16* __restrict__ HT, int ldht, int nseg,
                           bf16* __restrict__ X, int width) {
    int idx = blockIdx.x * 256 + threadIdx.x;
    if (idx >= NT * width) return;
    int m = idx / width, d = idx - m * width;
    float h = b2f(HT[(size_t)m * ldht + d]);
    float t = b2f(HT[(size_t)m * ldht + nseg + d]);
    float x = b2f(X[idx]);
    X[idx] = __float2bfloat16(t * h + (1.f - t) * x);
}

// ---------------------------------------------------------------------------
// Transpose x2-halves of two [NT,P] matrices into [B,P,S]; y selects (P,Q).
// ---------------------------------------------------------------------------
__global__ void k_transpose2(const bf16* __restrict__ srcP, bf16* __restrict__ dstP,
                             const bf16* __restrict__ srcQ, bf16* __restrict__ dstQ) {
    int idx = blockIdx.x * 256 + threadIdx.x;
    if (idx >= B_ * P_ * S_) return;
    const bf16* src = blockIdx.y ? srcQ : srcP;
    bf16* dst = blockIdx.y ? dstQ : dstP;
    int j = idx & (S_ - 1);
    int rest = idx >> 7;
    int p = rest % P_;
    int b = rest / P_;
    dst[idx] = src[((size_t)(b * S_ + j)) * P_ + p];
}

// ---------------------------------------------------------------------------
// sim[b,i,j] = dot_p(p1,p2) + sum_p 1/(1+|q1-q2|)
// Grid: 32 b x 16 i-tiles (8 rows). 256 threads: j = tid&127, h = tid>>7
// handles 4 i rows. LDS: interleaved {q1,p1} per (i,p) -> one broadcast
// ds_read_b64 per term-pair. Fast rcp (no IEEE refine).
// ---------------------------------------------------------------------------
__global__ __launch_bounds__(256) void k_sim2(const bf16* __restrict__ Pmat,
                                              const bf16* __restrict__ Qmat,
                                              const bf16* __restrict__ PT,
                                              const bf16* __restrict__ QT,
                                              float* __restrict__ SIM) {
    __shared__ float qp[8][P_][2];   // [i][p][{q1,p1}] = 12.8 KB
    int blk = blockIdx.x;
    int b = blk >> 4;
    int it = blk & 15;
    int tid = threadIdx.x;
    int j = tid & 127, h = tid >> 7;
    int row0 = b * 128 + it * 8;     // global x1-token row base (0..4095)
    for (int x = tid; x < 8 * P_; x += 256) {
        int r = x / P_, c = x - r * P_;
        qp[r][c][0] = b2f(Qmat[(size_t)(row0 + r) * P_ + c]);
        qp[r][c][1] = b2f(Pmat[(size_t)(row0 + r) * P_ + c]);
    }
    __syncthreads();
    const bf16* ptb = PT + (size_t)b * P_ * S_;
    const bf16* qtb = QT + (size_t)b * P_ * S_;
    float acc[4] = {0.f, 0.f, 0.f, 0.f};
    for (int p = 0; p < P_; ++p) {
        float v = b2f(ptb[p * S_ + j]);
        float u = b2f(qtb[p * S_ + j]);
#pragma unroll
        for (int r = 0; r < 4; ++r) {
            int i = h * 4 + r;
            float2 w = *(const float2*)&qp[i][p][0];
            float d = w.x - u;
            acc[r] += w.y * v + __builtin_amdgcn_rcpf(1.f + fabsf(d));
        }
    }
#pragma unroll
    for (int r = 0; r < 4; ++r) {
        int i = it * 8 + h * 4 + r;
        SIM[((size_t)(b * 128 + i)) * S_ + j] = acc[r];
    }
}

// ---------------------------------------------------------------------------
// Merged softmax-weighted average: grid 8192 = 4096 beta + 4096 alpha.
// 256 threads: t<128 do softmax; t<150 compute 2 d-columns each via uint
// (bf16-pair) loads and packed stores.
// ---------------------------------------------------------------------------
__global__ __launch_bounds__(256) void k_av2(const float* __restrict__ SIM,
                                             const bf16* __restrict__ E,
                                             bf16* __restrict__ OUT) {
    int blk = blockIdx.x;
    int kind = blk >> 12;            // 0 = beta (rows), 1 = alpha (cols)
    int blk2 = blk & 4095;
    int b = blk2 >> 7, r = blk2 & 127;
    int t = threadIdx.x;
    __shared__ float w[S_];
    __shared__ float red[S_];
    float x = 0.f;
    if (t < 128) {
        x = (kind == 0) ? SIM[(size_t)blk2 * S_ + t]
                        : SIM[((size_t)b * S_ + t) * S_ + r];
        red[t] = x;
    }
    __syncthreads();
    for (int s = 64; s > 0; s >>= 1) {
        if (t < s) red[t] = fmaxf(red[t], red[t + s]);
        __syncthreads();
    }
    float mx = red[0];
    __syncthreads();
    float ex = 0.f;
    if (t < 128) { ex = expf(x - mx); red[t] = ex; }
    __syncthreads();
    for (int s = 64; s > 0; s >>= 1) {
        if (t < s) red[t] += red[t + s];
        __syncthreads();
    }
    if (t < 128) w[t] = ex / red[0];
    __syncthreads();
    if (t < 150) {
        const bf16* Esrc = E + (kind == 0 ? (size_t)NT1 * D_ : 0) + (size_t)b * S_ * D_;
        bf16* orow = OUT + (kind == 0 ? (size_t)blk2 * D_ : (size_t)(NT1 + blk2) * D_);
        const unsigned short* ebase = (const unsigned short*)Esrc + 2 * t;
        float a0 = 0.f, a1 = 0.f;
        for (int s = 0; s < S_; ++s) {
            unsigned int uv = *(const unsigned int*)(ebase + (size_t)s * D_);
            float lo = __uint_as_float(uv << 16);
            float hi = __uint_as_float(uv & 0xffff0000u);
            float ws = w[s];
            a0 += ws * lo;
            a1 += ws * hi;
        }
        unsigned int o = (unsigned int)(unsigned short)f2s(a0)
                       | ((unsigned int)(unsigned short)f2s(a1) << 16);
        *(unsigned int*)((unsigned short*)orow + 2 * t) = o;
    }
}

// ---------------------------------------------------------------------------
// Pool: out[b] = concat(max_i v1, max_j v2, sum_i v1, sum_j v2)  [B,4P] fp32
// ---------------------------------------------------------------------------
__global__ __launch_bounds__(256) void k_pool(const bf16* __restrict__ V,
                                              float* __restrict__ OUT) {
    int b = blockIdx.x;
    int c = threadIdx.x;
    if (c >= P_) return;
    const bf16* v1 = V + (size_t)b * S_ * P_;
    const bf16* v2 = V + (size_t)(NT1 + b * S_) * P_;
    float mx1 = -INFINITY, mx2 = -INFINITY, s1 = 0.f, s2 = 0.f;
    for (int i = 0; i < S_; ++i) {
        float a = b2f(v1[(size_t)i * P_ + c]);
        mx1 = fmaxf(mx1, a); s1 += a;
        float bb = b2f(v2[(size_t)i * P_ + c]);
        mx2 = fmaxf(mx2, bb); s2 += bb;
    }
    float* o = OUT + (size_t)b * 4 * P_;
    o[c] = mx1; o[P_ + c] = mx2; o[2 * P_ + c] = s1; o[3 * P_ + c] = s2;
}

// Sentinel fill (diagnostic: absmax ~555 => ws_size too small)
__global__ void k_fillf(float* dst, int n, float v) {
    int i = blockIdx.x * 256 + threadIdx.x;
    if (i < n) dst[i] = v;
}

// ---------------------------------------------------------------------------
// Launch
// ---------------------------------------------------------------------------
extern "C" void kernel_launch(void* const* d_in, const int* in_sizes, int n_in,
                              void* d_out, int out_size, void* d_ws, size_t ws_size,
                              hipStream_t stream) {
    const int* x1 = (const int*)d_in[0];
    const int* x2 = (const int*)d_in[1];
    const float* emb = (const float*)d_in[2];
    const float *hw1_Wh = (const float*)d_in[3],  *hw1_bh = (const float*)d_in[4];
    const float *hw1_Wt = (const float*)d_in[5],  *hw1_bt = (const float*)d_in[6];
    const float *hw2_Wh = (const float*)d_in[7],  *hw2_bh = (const float*)d_in[8];
    const float *hw2_Wt = (const float*)d_in[9],  *hw2_bt = (const float*)d_in[10];
    const float *mul_W1 = (const float*)d_in[11], *mul_b1 = (const float*)d_in[12];
    const float *mul_W2 = (const float*)d_in[13], *mul_b2 = (const float*)d_in[14];
    const float *dist_W1 = (const float*)d_in[15], *dist_b1 = (const float*)d_in[16];
    const float *dist_W2 = (const float*)d_in[17], *dist_b2 = (const float*)d_in[18];
    const float *cmp_W1 = (const float*)d_in[19], *cmp_b1 = (const float*)d_in[20];
    const float *cmp_W2 = (const float*)d_in[21], *cmp_b2 = (const float*)d_in[22];
    const float *chw1_Wh = (const float*)d_in[23], *chw1_bh = (const float*)d_in[24];
    const float *chw1_Wt = (const float*)d_in[25], *chw1_bt = (const float*)d_in[26];
    const float *chw2_Wh = (const float*)d_in[27], *chw2_bh = (const float*)d_in[28];
    const float *chw2_Wt = (const float*)d_in[29], *chw2_bt = (const float*)d_in[30];
    const float *agg_W1 = (const float*)d_in[31], *agg_b1 = (const float*)d_in[32];
    const float *agg_W2 = (const float*)d_in[33], *agg_b2 = (const float*)d_in[34];
    const float *out_W = (const float*)d_in[35], *out_b = (const float*)d_in[36];

    // ---- Workspace layout (elems) ----
    const size_t nED = (size_t)NT * D_;        // 2,457,600
    const size_t nEP = (size_t)NT * P_;        // 1,638,400
    const size_t nCht = (size_t)NT * 600;      // 4,915,200
    const size_t nCat = (size_t)NT * 1216;     // 9,961,472
    const size_t nTR = (size_t)B_ * P_ * S_;   //   819,200
    const size_t nWT = 1286144;                // converted bf16 weights total
    const size_t nWTf = 200600;                // fp32 transposed tail weights
    size_t bf16_elems = 2 * nED + 2 * nEP + nCht + nCat + nWT;
    size_t f32_elems = (size_t)B_ * 4 * P_ + 2 * (size_t)B_ * P_ + nWTf;
    size_t need = bf16_elems * 2 + f32_elems * 4 + 64;
    if (ws_size < need) {
        k_fillf<<<dim3(1), dim3(256), 0, stream>>>((float*)d_out, B_ * 3, 555.f);
        return;
    }
    bf16* Eb  = (bf16*)d_ws;            // [NT,300]
    bf16* A2b = Eb + nED;               // [NT,300] ATT
    bf16* Pb  = A2b + nED;              // [NT,200] mul proj -> V
    bf16* Qb  = Pb + nEP;               // [NT,200] dist proj
    bf16* Cht = Qb + nEP;               // [NT,600] packed h|t / hidden / PT/QT/SIM
    bf16* CatB = Cht + nCht;            // [NT,1216] dense concat features
    bf16* WTp = CatB + nCat;            // converted bf16 weights pool
    float* POOL = (float*)(WTp + nWT);  // [B,4P]
    float* G1 = POOL + (size_t)B_ * 4 * P_;
    float* G2 = G1 + (size_t)B_ * P_;
    float* WT_a1 = G2 + (size_t)B_ * P_;  // [200][800] fp32
    float* WT_a2 = WT_a1 + 160000;        // [200][200] fp32
    float* WT_o  = WT_a2 + 40000;         // [3][200] fp32
    // overlays inside Cht:
    bf16* PTb = Cht;
    bf16* QTb = Cht + nTR;
    float* SIM = (float*)(Cht + 2 * nTR);

    // converted-weight sub-buffers (elems), Npad mult of 128
    bf16* WT_hw1 = WTp + 0;        // 640x320
    bf16* WT_hw2 = WTp + 204800;   // 640x320
    bf16* WT_md  = WTp + 409600;   // 512x320 (mul_W1 | dist_W1)
    bf16* WT_m2  = WTp + 573440;   // 256x224
    bf16* WT_d2  = WTp + 630784;   // 256x224
    bf16* WT_c1  = WTp + 688128;   // 256x1216
    bf16* WT_c2  = WTp + 999424;   // 256x224
    bf16* WT_ch1 = WTp + 1056768;  // 512x224 (chw1_Wh | chw1_Wt)
    bf16* WT_ch2 = WTp + 1171456;  // 512x224

    dim3 blk256(256);

    // 0. weight conversions
    ConvTable T;
    const float* s1[9] = {hw1_Wh, hw2_Wh, mul_W1, mul_W2, dist_W2, cmp_W1, cmp_W2, chw1_Wh, chw2_Wh};
    const float* s2[9] = {hw1_Wt, hw2_Wt, dist_W1, nullptr, nullptr, nullptr, nullptr, chw1_Wt, chw2_Wt};
    bf16* dsts[9] = {WT_hw1, WT_hw2, WT_md, WT_m2, WT_d2, WT_c1, WT_c2, WT_ch1, WT_ch2};
    int Ks[9]  = {300, 300, 300, 200, 200, 1200, 200, 200, 200};
    int N1s[9] = {300, 300, 200, 200, 200, 200, 200, 200, 200};
    int N2s[9] = {300, 300, 200, 0, 0, 0, 0, 200, 200};
    int Kps[9] = {320, 320, 320, 224, 224, 1216, 224, 224, 224};
    int Nps[9] = {640, 640, 512, 256, 256, 256, 256, 512, 512};
    unsigned long long base = 0;
    for (int i = 0; i < 9; ++i) {
        T.W1[i] = s1[i]; T.W2[i] = s2[i]; T.dst[i] = dsts[i];
        T.K[i] = Ks[i]; T.N1[i] = N1s[i]; T.N2[i] = N2s[i]; T.Kpad[i] = Kps[i];
        T.base[i] = base;
        base += (unsigned long long)Kps[i] * Nps[i];
    }
    T.total = base;   // 1,286,144
    k_convw<<<dim3((unsigned)((base + 255) / 256)), blk256, 0, stream>>>(T);
    k_convt<<<dim3((200600 + 255) / 256), blk256, 0, stream>>>(agg_W1, agg_W2, out_W,
                                                               WT_a1, WT_a2, WT_o);

    // 1. embed
    k_embed<<<dim3((NT * D_ + 255) / 256), blk256, 0, stream>>>(x1, x2, emb, Eb);

    int hwyD = (NT * D_ + 255) / 256, hwyP = (NT * P_ + 255) / 256;

    // 2-3. embedding highway stack: combined h|t GEMM (N=600) + combine
    k_mfma_gemm<<<dim3(5, 128), blk256, 0, stream>>>(Eb, 300, WT_hw1, 320, 300,
        Cht, 600, 600, 300, hw1_bh, hw1_bt, 1, 2);
    k_highway2<<<dim3(hwyD), blk256, 0, stream>>>(Cht, 600, 300, Eb, 300);
    k_mfma_gemm<<<dim3(5, 128), blk256, 0, stream>>>(Eb, 300, WT_hw2, 320, 300,
        Cht, 600, 600, 300, hw2_bh, hw2_bt, 1, 2);
    k_highway2<<<dim3(hwyD), blk256, 0, stream>>>(Cht, 600, 300, Eb, 300);

    // 4-5. mul+dist W1 combined (N=400) -> Cht; then W2s -> Pb, Qb
    k_mfma_gemm<<<dim3(4, 128), blk256, 0, stream>>>(Eb, 300, WT_md, 320, 300,
        Cht, 400, 400, 200, mul_b1, dist_b1, 1, 1);
    k_mfma_gemm<<<dim3(2, 128), blk256, 0, stream>>>(Cht, 400, WT_m2, 224, 200,
        Pb, 200, 200, 200, mul_b2, mul_b2, 1, 1);
    k_mfma_gemm<<<dim3(2, 128), blk256, 0, stream>>>(Cht + 200, 400, WT_d2, 224, 200,
        Qb, 200, 200, 200, dist_b2, dist_b2, 1, 1);

    // 6. transpose x2-halves into Cht overlay (one dispatch, y selects P/Q)
    int nTRb = (int)((nTR + 255) / 256);
    k_transpose2<<<dim3(nTRb, 2), blk256, 0, stream>>>(
        Pb + (size_t)NT1 * P_, PTb, Qb + (size_t)NT1 * P_, QTb);

    // 7. sim (i-tiled, LDS-broadcast, fast rcp)
    k_sim2<<<dim3(B_ * 16), blk256, 0, stream>>>(Pb, Qb, PTb, QTb, SIM);

    // 8. attention (merged beta+alpha): beta -> A2b rows 0..4095, alpha -> 4096..8191
    k_av2<<<dim3(2 * NT1), blk256, 0, stream>>>(SIM, Eb, A2b);

    // 9. compare ff: dense concat, then plain GEMMs (K=1216 incl zero pad)
    k_cat<<<dim3((NT * 304 + 255) / 256), blk256, 0, stream>>>(Eb, A2b, CatB);
    k_mfma_gemm<<<dim3(2, 128), blk256, 0, stream>>>(CatB, 1216, WT_c1, 1216, 1216,
        Cht, 200, 200, 200, cmp_b1, cmp_b1, 1, 1);
    k_mfma_gemm<<<dim3(2, 128), blk256, 0, stream>>>(Cht, 200, WT_c2, 224, 200,
        Pb, 200, 200, 200, cmp_b2, cmp_b2, 1, 1);

    // 10-11. compare highway stack (combined N=400 GEMMs)
    k_mfma_gemm<<<dim3(4, 128), blk256, 0, stream>>>(Pb, 200, WT_ch1, 224, 200,
        Cht, 400, 400, 200, chw1_bh, chw1_bt, 1, 2);
    k_highway2<<<dim3(hwyP), blk256, 0, stream>>>(Cht, 400, 200, Pb, 200);
    k_mfma_gemm<<<dim3(4, 128), blk256, 0, stream>>>(Pb, 200, WT_ch2, 224, 200,
        Cht, 400, 400, 200, chw2_bh, chw2_bt, 1, 2);
    k_highway2<<<dim3(hwyP), blk256, 0, stream>>>(Cht, 400, 200, Pb, 200);

    // 12. pool
    k_pool<<<dim3(B_), blk256, 0, stream>>>(Pb, POOL);

    // 13-15. aggregate ff + final linear: wave-per-output skinny GEMMs
    k_skinny<<<dim3(1600), blk256, 0, stream>>>(POOL, WT_a1, agg_b1, G1, B_, P_, 800, 1);
    k_skinny<<<dim3(1600), blk256, 0, stream>>>(G1, WT_a2, agg_b2, G2, B_, P_, 200, 1);
    k_skinny<<<dim3(24), blk256, 0, stream>>>(G2, WT_o, out_b, (float*)d_out, B_, 3, 200, 0);
}